// Round 4
// baseline (331.430 us; speedup 1.0000x reference)
//
#include <hip/hip_runtime.h>
#include <math.h>

// ---- static config (mirrors reference) ----
constexpr int BB  = 32;     // batch
constexpr int MM  = 20;     // max gt per image
constexpr int NCC = 80;     // classes
constexpr int RM  = 16;     // reg_max
constexpr int NOC = 144;    // channels per head
constexpr int AT  = 8400;   // anchors
constexpr int TK  = 10;     // topk
constexpr int BA  = BB * AT;  // 268800
constexpr int BM  = BB * MM;  // 640
constexpr int MAXPOS = BM * TK; // 6400 max positive anchors
constexpr float EPS_A = 1e-9f;
constexpr float VCOEF = 0.40528473456935108577551785283891f; // 4/pi^2

struct Lvl { const float* f; int o, w, hw; float s; };

__device__ inline Lvl level_of(int a, const float* f0, const float* f1, const float* f2){
  Lvl L;
  if (a < 6400)      { L.f = f0; L.o = a;        L.w = 80; L.hw = 6400; L.s = 8.f;  }
  else if (a < 8000) { L.f = f1; L.o = a - 6400; L.w = 40; L.hw = 1600; L.s = 16.f; }
  else               { L.f = f2; L.o = a - 8000; L.w = 20; L.hw = 400;  L.s = 32.f; }
  return L;
}

__device__ inline float frcp(float x){ return __builtin_amdgcn_rcpf(x); }

// fast atan, |err| < ~2e-6
__device__ inline float fast_atan(float x){
  float ax = fabsf(x);
  bool big = ax > 1.f;
  float z = big ? frcp(ax) : ax;
  float z2 = z * z;
  float p = fmaf(z2, -0.0117212f, 0.0526533f);
  p = fmaf(z2, p, -0.1164329f);
  p = fmaf(z2, p, 0.1935435f);
  p = fmaf(z2, p, -0.3326235f);
  p = fmaf(z2, p, 0.9999773f);
  float r = z * p;
  r = big ? 1.57079632679f - r : r;
  return copysignf(r, x);
}

__device__ inline float ciou_f(float b1x1,float b1y1,float b1x2,float b1y2,
                               float b2x1,float b2y1,float b2x2,float b2y2){
  const float eps = 1e-7f;
  float w1 = b1x2 - b1x1, h1 = b1y2 - b1y1 + eps;
  float w2 = b2x2 - b2x1, h2 = b2y2 - b2y1 + eps;
  float iw = fmaxf(fminf(b1x2, b2x2) - fmaxf(b1x1, b2x1), 0.f);
  float ih = fmaxf(fminf(b1y2, b2y2) - fmaxf(b1y1, b2y1), 0.f);
  float inter = iw * ih;
  float uni = w1 * h1 + w2 * h2 - inter + eps;
  float iou = inter * frcp(uni);
  float cw = fmaxf(b1x2, b2x2) - fminf(b1x1, b2x1);
  float ch = fmaxf(b1y2, b2y2) - fminf(b1y1, b2y1);
  float c2 = cw * cw + ch * ch + eps;
  float dx = b2x1 + b2x2 - b1x1 - b1x2;
  float dy = b2y1 + b2y2 - b1y1 - b1y2;
  float rho2 = (dx * dx + dy * dy) * 0.25f;
  float r1 = w1 * frcp(h1), r2 = w2 * frcp(h2);
  float dat = fast_atan((r2 - r1) * frcp(fmaf(r1, r2, 1.f)));
  float v = VCOEF * dat * dat;
  float alpha = v * frcp(v - iou + (1.0f + eps));
  return iou - (rho2 * frcp(c2) + v * alpha);
}

__device__ inline unsigned long long shfl_xor_u64(unsigned long long v, int mask){
  int lo = __shfl_xor((int)(unsigned)(v & 0xFFFFFFFFull), mask);
  int hi = __shfl_xor((int)(unsigned)(v >> 32), mask);
  return ((unsigned long long)(unsigned)hi << 32) | (unsigned)lo;
}

__device__ inline void topk_insert(unsigned long long* top, unsigned long long key){
#pragma unroll
  for (int k = 0; k < TK; k++){
    unsigned long long cur = top[k];
    bool gt = key > cur;
    top[k] = gt ? key : cur;
    key    = gt ? cur : key;
  }
}

// ---------------- kernel 1: preprocess targets ----------------
__global__ void k_prep(const float* __restrict__ tgt, float* __restrict__ out5,
                       float* __restrict__ gtbox, int* __restrict__ gtlab,
                       float* __restrict__ gtmask, int* __restrict__ pa_i,
                       int* __restrict__ po_i, double* __restrict__ acc){
  int t = threadIdx.x; // 0..639
  for (int i = t; i < BM * 5; i += 640) out5[i] = 0.f;
  if (t < 8) acc[t] = 0.0;
  pa_i[t] = 0; po_i[t] = 0;
  __syncthreads();
  {
    int img = (int)tgt[t * 6 + 0];
    int j = t;
    while (j > 0 && (int)tgt[(j - 1) * 6 + 0] == img) j--;
    int pos = t - j;
    if (img >= 0 && img < BB && pos < MM){
      for (int k = 0; k < 5; k++)
        out5[(img * MM + pos) * 5 + k] = tgt[t * 6 + 1 + k];
    }
  }
  __syncthreads();
  {
    float lab = out5[t * 5 + 0];
    float cx = out5[t * 5 + 1] * 640.f;
    float cy = out5[t * 5 + 2] * 640.f;
    float w  = out5[t * 5 + 3] * 640.f;
    float h  = out5[t * 5 + 4] * 640.f;
    float x1 = cx - w * 0.5f, y1 = cy - h * 0.5f;
    float x2 = cx + w * 0.5f, y2 = cy + h * 0.5f;
    gtbox[t * 4 + 0] = x1; gtbox[t * 4 + 1] = y1;
    gtbox[t * 4 + 2] = x2; gtbox[t * 4 + 3] = y2;
    gtlab[t] = (int)lab;
    gtmask[t] = ((x1 + y1 + x2 + y2) > 0.f) ? 1.f : 0.f;
  }
}

// ---------------- kernel 2: DFL decode + softplus sum ----------------
// 2 anchors per thread, float2 channel loads, per-side register buffering.
__global__ __launch_bounds__(256, 2) void k_decode(
    const float* __restrict__ f0, const float* __restrict__ f1,
    const float* __restrict__ f2,
    float4* __restrict__ pbox, float4* __restrict__ lse,
    double* __restrict__ acc){
  int gid = blockIdx.x * 256 + threadIdx.x;   // 0 .. BA/2-1 (grid exact)
  int b = gid / (AT / 2);
  int g = gid - b * (AT / 2);
  int a = g * 2;
  Lvl L = level_of(a, f0, f1, f2);
  const float* base = L.f + (size_t)b * NOC * L.hw + L.o;
  int o0 = L.o, o1 = L.o + 1;
  int iy0 = o0 / L.w, iy1 = o1 / L.w;
  float ax0 = (float)(o0 - iy0 * L.w) + 0.5f, ay0 = (float)iy0 + 0.5f;
  float ax1 = (float)(o1 - iy1 * L.w) + 0.5f, ay1 = (float)iy1 + 0.5f;
  float d0[4], d1[4], ls0[4], ls1[4];
#pragma unroll
  for (int s = 0; s < 4; s++){
    float2 xs[16];
#pragma unroll
    for (int j = 0; j < 16; j++)
      xs[j] = *(const float2*)(base + (size_t)(s * 16 + j) * L.hw);
    float mx0 = -1e30f, mx1 = -1e30f;
#pragma unroll
    for (int j = 0; j < 16; j++){
      mx0 = fmaxf(mx0, xs[j].x);
      mx1 = fmaxf(mx1, xs[j].y);
    }
    float sm0 = 0.f, dt0 = 0.f, sm1 = 0.f, dt1 = 0.f;
#pragma unroll
    for (int j = 0; j < 16; j++){
      float e0 = __expf(xs[j].x - mx0); sm0 += e0; dt0 += e0 * (float)j;
      float e1 = __expf(xs[j].y - mx1); sm1 += e1; dt1 += e1 * (float)j;
    }
    d0[s] = dt0 * frcp(sm0); ls0[s] = mx0 + __logf(sm0);
    d1[s] = dt1 * frcp(sm1); ls1[s] = mx1 + __logf(sm1);
  }
  int idx = b * AT + a;
  pbox[idx]     = make_float4(ax0 - d0[0], ay0 - d0[1], ax0 + d0[2], ay0 + d0[3]);
  pbox[idx + 1] = make_float4(ax1 - d1[0], ay1 - d1[1], ax1 + d1[2], ay1 + d1[3]);
  lse[idx]      = make_float4(ls0[0], ls0[1], ls0[2], ls0[3]);
  lse[idx + 1]  = make_float4(ls1[0], ls1[1], ls1[2], ls1[3]);
  float sp = 0.f;
  const float* cb = base + (size_t)(4 * RM) * L.hw;
#pragma unroll 16
  for (int c = 0; c < NCC; c++){
    float2 xv = *(const float2*)(cb + (size_t)c * L.hw);
    sp += fmaxf(xv.x, 0.f) + __logf(1.f + __expf(-fabsf(xv.x)));
    sp += fmaxf(xv.y, 0.f) + __logf(1.f + __expf(-fabsf(xv.y)));
  }
  for (int off = 32; off; off >>= 1) sp += __shfl_down(sp, off);
  __shared__ float red[4];
  int wid = threadIdx.x >> 6, lid = threadIdx.x & 63;
  if (lid == 0) red[wid] = sp;
  __syncthreads();
  if (threadIdx.x == 0){
    float tot = red[0] + red[1] + red[2] + red[3];
    atomicAdd(&acc[4], (double)tot);
  }
}

// ---------------- kernel 3: candidate-rect top-10 + scatter ----------------
// one block per (b,m); three compile-time level passes (no dynamic-indexed
// local arrays -> no scratch); exact magic-mul division for row index.
__global__ __launch_bounds__(256, 2) void k_align(
    const float* __restrict__ f0, const float* __restrict__ f1,
    const float* __restrict__ f2, const float4* __restrict__ pbox,
    const float* __restrict__ gtbox, const int* __restrict__ gtlab,
    const float* __restrict__ gtmask,
    unsigned* __restrict__ mpos, unsigned* __restrict__ list,
    int* __restrict__ count){
  int pair = blockIdx.x;
  int b = pair / MM, m = pair % MM;
  if (gtmask[pair] <= 0.f) return;  // block-uniform exit
  int tid = threadIdx.x;
  float gx1 = gtbox[pair * 4 + 0], gy1 = gtbox[pair * 4 + 1];
  float gx2 = gtbox[pair * 4 + 2], gy2 = gtbox[pair * 4 + 3];
  int lab = gtlab[pair];
  unsigned long long top[TK];
#pragma unroll
  for (int k = 0; k < TK; k++) top[k] = 0ULL;

#define PROC_LEVEL(FPTR, W, HW, AOFF, S)                                      \
  {                                                                           \
    const float s_ = (S); const float inv_ = 1.f / (S);                       \
    int x0 = max(0, (int)floorf(gx1 * inv_ - 0.5f));                          \
    int x1 = min((W) - 1, (int)ceilf(gx2 * inv_ - 0.5f));                     \
    int y0 = max(0, (int)floorf(gy1 * inv_ - 0.5f));                          \
    int y1 = min((W) - 1, (int)ceilf(gy2 * inv_ - 0.5f));                     \
    int nxx = x1 - x0 + 1, nyy = y1 - y0 + 1;                                 \
    if (nxx > 0 && nyy > 0){                                                  \
      int ntot = nxx * nyy;                                                   \
      unsigned magic = 0xFFFFFFFFu / (unsigned)nxx + 1u;                      \
      const float* clsrow = (FPTR) + (size_t)b * NOC * (HW)                   \
                            + (size_t)(4 * RM + lab) * (HW);                  \
      for (int t = tid; t < ntot; t += 256){                                  \
        int iy = (int)(((unsigned long long)(unsigned)t * magic) >> 32);      \
        int ix = t - iy * nxx + x0;                                           \
        iy += y0;                                                             \
        float ax = ((float)ix + 0.5f) * s_;                                   \
        float ay = ((float)iy + 0.5f) * s_;                                   \
        float mn = fminf(fminf(ax - gx1, ay - gy1),                           \
                         fminf(gx2 - ax, gy2 - ay));                          \
        if (mn > EPS_A){                                                      \
          int o = iy * (W) + ix;                                              \
          int a = (AOFF) + o;                                                 \
          float4 pb = pbox[b * AT + a];                                       \
          float c = ciou_f(gx1, gy1, gx2, gy2,                                \
                           pb.x * s_, pb.y * s_, pb.z * s_, pb.w * s_);       \
          float ovl = fmaxf(c, 0.f);                                          \
          if (ovl > 0.f){                                                     \
            float xv = clsrow[o];                                             \
            float sc = frcp(1.f + __expf(-xv));                               \
            float o2 = ovl * ovl;                                             \
            float aln = sqrtf(sc) * (o2 * o2 * o2);                           \
            if (aln > 0.f){                                                   \
              unsigned long long key =                                        \
                ((unsigned long long)__float_as_uint(aln) << 32) |            \
                (unsigned long long)(0xFFFFFFFFu - (unsigned)a);              \
              topk_insert(top, key);                                          \
            }                                                                 \
          }                                                                   \
        }                                                                     \
      }                                                                       \
    }                                                                         \
  }

  PROC_LEVEL(f0, 80, 6400, 0, 8.f)
  PROC_LEVEL(f1, 40, 1600, 6400, 16.f)
  PROC_LEVEL(f2, 20, 400, 8000, 32.f)
#undef PROC_LEVEL

  for (int xm = 1; xm < 64; xm <<= 1){
    unsigned long long oth[TK];
#pragma unroll
    for (int k = 0; k < TK; k++) oth[k] = shfl_xor_u64(top[k], xm);
#pragma unroll
    for (int k = 0; k < TK; k++) topk_insert(top, oth[k]);
  }
  __shared__ unsigned long long s_keys[4 * TK];
  int wid = tid >> 6, lid = tid & 63;
  if (lid == 0){
#pragma unroll
    for (int k = 0; k < TK; k++) s_keys[wid * TK + k] = top[k];
  }
  __syncthreads();
  if (tid == 0){
    unsigned long long fin[TK];
#pragma unroll
    for (int k = 0; k < TK; k++) fin[k] = s_keys[k];
    for (int i = TK; i < 4 * TK; i++) topk_insert(fin, s_keys[i]);
    for (int k = 0; k < TK; k++){
      unsigned a = 0xFFFFFFFFu - (unsigned)(fin[k] & 0xFFFFFFFFull);
      if (a < (unsigned)AT){
        unsigned old = atomicOr(&mpos[(size_t)b * AT + a], 1u << m);
        if (old == 0){
          int i = atomicAdd(count, 1);
          list[i] = ((unsigned)b << 14) | a;
        }
      }
    }
  }
}

// ---------------- kernel 4: resolve multi-claims, pos maxima (compact list) ----------------
__global__ __launch_bounds__(256) void k_resolve(
    const float* __restrict__ f0, const float* __restrict__ f1,
    const float* __restrict__ f2, const float4* __restrict__ pbox,
    const float* __restrict__ gtbox, const int* __restrict__ gtlab,
    const float* __restrict__ gtmask, const unsigned* __restrict__ mpos,
    const unsigned* __restrict__ list, const int* __restrict__ count,
    unsigned* __restrict__ list_m, float* __restrict__ list_aln,
    int* __restrict__ pa_i, int* __restrict__ po_i){
  int i = blockIdx.x * 256 + threadIdx.x;
  if (i >= *count) return;
  unsigned pk = list[i];
  int b = pk >> 14, a = pk & 0x3FFF;
  unsigned bits = mpos[(size_t)b * AT + a];
  Lvl L = level_of(a, f0, f1, f2);
  float ax = ((float)(L.o % L.w) + 0.5f) * L.s;
  float ay = ((float)(L.o / L.w) + 0.5f) * L.s;
  float4 pb = pbox[b * AT + a];
  float px1 = pb.x * L.s, py1 = pb.y * L.s, px2 = pb.z * L.s, py2 = pb.w * L.s;
  int m; float ovl;
  if (__popc(bits) > 1){
    float best = -1.f; int bm = 0;
    for (int mm = 0; mm < MM; mm++){
      float v = 0.f;
      if (gtmask[b * MM + mm] > 0.f){
        float x1 = gtbox[(b * MM + mm) * 4 + 0], y1 = gtbox[(b * MM + mm) * 4 + 1];
        float x2 = gtbox[(b * MM + mm) * 4 + 2], y2 = gtbox[(b * MM + mm) * 4 + 3];
        float mn = fminf(fminf(ax - x1, ay - y1), fminf(x2 - ax, y2 - ay));
        if (mn > EPS_A)
          v = fmaxf(ciou_f(x1, y1, x2, y2, px1, py1, px2, py2), 0.f);
      }
      if (v > best){ best = v; bm = mm; }
    }
    m = bm; ovl = fmaxf(best, 0.f);
  } else {
    m = __ffs(bits) - 1;
    float x1 = gtbox[(b * MM + m) * 4 + 0], y1 = gtbox[(b * MM + m) * 4 + 1];
    float x2 = gtbox[(b * MM + m) * 4 + 2], y2 = gtbox[(b * MM + m) * 4 + 3];
    ovl = fmaxf(ciou_f(x1, y1, x2, y2, px1, py1, px2, py2), 0.f);
  }
  int lab = gtlab[b * MM + m];
  float xv = L.f[(size_t)b * NOC * L.hw + (size_t)(4 * RM + lab) * L.hw + L.o];
  float sc = frcp(1.f + __expf(-xv));
  float o2 = ovl * ovl;
  float aln = sqrtf(sc) * (o2 * o2 * o2);
  list_m[i] = (unsigned)m;
  list_aln[i] = aln;
  atomicMax(&pa_i[b * MM + m], __float_as_int(aln));
  atomicMax(&po_i[b * MM + m], __float_as_int(ovl));
}

// ---------------- kernel 5: per-positive losses (compact list) ----------------
__global__ __launch_bounds__(256) void k_final(
    const float* __restrict__ f0, const float* __restrict__ f1,
    const float* __restrict__ f2,
    const float4* __restrict__ pbox, const float4* __restrict__ lse,
    const float* __restrict__ gtbox, const int* __restrict__ gtlab,
    const int* __restrict__ pa_i, const int* __restrict__ po_i,
    const unsigned* __restrict__ list, const unsigned* __restrict__ list_m,
    const float* __restrict__ list_aln, const int* __restrict__ count,
    double* __restrict__ acc){
  int i = blockIdx.x * 256 + threadIdx.x;
  float w_ = 0.f, clsp = 0.f, boxp = 0.f, dflp = 0.f;
  if (i < *count){
    unsigned pk = list[i];
    int b = pk >> 14, a = pk & 0x3FFF;
    int m = (int)list_m[i];
    float aln = list_aln[i];
    float pa = __int_as_float(pa_i[b * MM + m]);
    float po = __int_as_float(po_i[b * MM + m]);
    w_ = aln * po * frcp(pa + EPS_A);
    Lvl L = level_of(a, f0, f1, f2);
    const float* base = L.f + (size_t)b * NOC * L.hw + L.o;
    float ax = (float)(L.o % L.w) + 0.5f;
    float ay = (float)(L.o / L.w) + 0.5f;
    float inv_s = frcp(L.s);
    float tx1 = gtbox[(b * MM + m) * 4 + 0] * inv_s, ty1 = gtbox[(b * MM + m) * 4 + 1] * inv_s;
    float tx2 = gtbox[(b * MM + m) * 4 + 2] * inv_s, ty2 = gtbox[(b * MM + m) * 4 + 3] * inv_s;
    float4 pb = pbox[b * AT + a];
    float iou = ciou_f(pb.x, pb.y, pb.z, pb.w, tx1, ty1, tx2, ty2);
    boxp = (1.f - iou) * w_;
    float4 L4 = lse[b * AT + a];
    float lsv[4] = { L4.x, L4.y, L4.z, L4.w };
    float tv[4] = { ax - tx1, ay - ty1, tx2 - ax, ty2 - ay };
    float dfl = 0.f;
#pragma unroll
    for (int s4 = 0; s4 < 4; s4++){
      float t = fminf(fmaxf(tv[s4], 0.f), (float)(RM - 1) - 0.01f);
      int tl = (int)t;
      float wl = (float)(tl + 1) - t;
      float xl = base[(size_t)(s4 * RM + tl) * L.hw];
      float xr = base[(size_t)(s4 * RM + tl + 1) * L.hw];
      dfl += (lsv[s4] - xl) * wl + (lsv[s4] - xr) * (1.f - wl);
    }
    dflp = dfl * 0.25f * w_;
    int lab = gtlab[b * MM + m];
    clsp = base[(size_t)(4 * RM + lab) * L.hw] * w_;
  }
  __shared__ float red[4][4];
  float vals[4] = { w_, clsp, boxp, dflp };
  int wid = threadIdx.x >> 6, lid = threadIdx.x & 63;
#pragma unroll
  for (int j = 0; j < 4; j++){
    float v = vals[j];
    for (int off = 32; off; off >>= 1) v += __shfl_down(v, off);
    if (lid == 0) red[wid][j] = v;
  }
  __syncthreads();
  if (threadIdx.x == 0){
    float t0 = 0.f, t1 = 0.f, t2 = 0.f, t3 = 0.f;
    for (int w2 = 0; w2 < 4; w2++){
      t0 += red[w2][0]; t1 += red[w2][1]; t2 += red[w2][2]; t3 += red[w2][3];
    }
    atomicAdd(&acc[0], (double)t0);
    atomicAdd(&acc[1], (double)t1);
    atomicAdd(&acc[2], (double)t2);
    atomicAdd(&acc[3], (double)t3);
  }
}

// ---------------- kernel 6: finalize ----------------
__global__ void k_out(const double* __restrict__ acc, float* __restrict__ out){
  if (threadIdx.x == 0 && blockIdx.x == 0){
    double tss = acc[0] > 1.0 ? acc[0] : 1.0;
    double loss_box = acc[2] / tss;
    double loss_cls = (acc[4] - acc[1]) / tss;
    double loss_dfl = acc[3] / tss;
    float l0 = (float)(loss_box * 7.5);
    float l1 = (float)(loss_cls * 0.5);
    float l2 = (float)(loss_dfl * 1.5);
    out[0] = (l0 + l1 + l2) * 32.f;
    out[1] = l0;
    out[2] = l1;
    out[3] = l2;
  }
}

extern "C" void kernel_launch(void* const* d_in, const int* in_sizes, int n_in,
                              void* d_out, int out_size, void* d_ws, size_t ws_size,
                              hipStream_t stream) {
  const float* f0 = (const float*)d_in[0];
  const float* f1 = (const float*)d_in[1];
  const float* f2 = (const float*)d_in[2];
  const float* tg = (const float*)d_in[3];
  float* out = (float*)d_out;

  char* w = (char*)d_ws;
  size_t off = 0;
  auto alloc = [&](size_t bytes) -> void* {
    void* p = w + off;
    off += (bytes + 255) & ~(size_t)255;
    return p;
  };
  float4*   pbox    = (float4*)  alloc((size_t)BA * 16);
  float4*   lse     = (float4*)  alloc((size_t)BA * 16);
  float*    gtbox   = (float*)   alloc((size_t)BM * 16);
  int*      gtlab   = (int*)     alloc((size_t)BM * 4);
  float*    gtmask  = (float*)   alloc((size_t)BM * 4);
  float*    out5    = (float*)   alloc((size_t)BM * 20);
  unsigned* mpos    = (unsigned*)alloc((size_t)BA * 4);   // zeroed below (with count)
  int*      count   = (int*)     alloc(4);
  unsigned* list    = (unsigned*)alloc((size_t)MAXPOS * 4);
  unsigned* list_m  = (unsigned*)alloc((size_t)MAXPOS * 4);
  float*    list_aln= (float*)   alloc((size_t)MAXPOS * 4);
  int*      pa      = (int*)     alloc((size_t)BM * 4);
  int*      po      = (int*)     alloc((size_t)BM * 4);
  double*   acc     = (double*)  alloc(8 * 8);

  // zero mpos + count (contiguous in the arena)
  hipMemsetAsync(mpos, 0, (size_t)BA * 4 + 256, stream);

  k_prep<<<1, 640, 0, stream>>>(tg, out5, gtbox, gtlab, gtmask, pa, po, acc);
  k_decode<<<BA / 2 / 256, 256, 0, stream>>>(f0, f1, f2, pbox, lse, acc);
  k_align<<<BM, 256, 0, stream>>>(f0, f1, f2, pbox, gtbox, gtlab, gtmask,
                                  mpos, list, count);
  k_resolve<<<MAXPOS / 256, 256, 0, stream>>>(f0, f1, f2, pbox, gtbox, gtlab, gtmask,
                                              mpos, list, count, list_m, list_aln, pa, po);
  k_final<<<MAXPOS / 256, 256, 0, stream>>>(f0, f1, f2, pbox, lse, gtbox, gtlab,
                                            pa, po, list, list_m, list_aln, count, acc);
  k_out<<<1, 64, 0, stream>>>(acc, out);
}

// Round 5
// 331.028 us; speedup vs baseline: 1.0012x; 1.0012x over previous
//
#include <hip/hip_runtime.h>
#include <math.h>

// ---- static config (mirrors reference) ----
constexpr int BB  = 32;     // batch
constexpr int MM  = 20;     // max gt per image
constexpr int NCC = 80;     // classes
constexpr int RM  = 16;     // reg_max
constexpr int NOC = 144;    // channels per head
constexpr int AT  = 8400;   // anchors
constexpr int TK  = 10;     // topk
constexpr int BA  = BB * AT;  // 268800
constexpr int BM  = BB * MM;  // 640
constexpr int MAXPOS = BM * TK; // 6400 max positive anchors
constexpr int NSLOT = 1024;     // max candidates per gt (worst case ~936)
constexpr float EPS_A = 1e-9f;
constexpr float VCOEF = 0.40528473456935108577551785283891f; // 4/pi^2

struct Lvl { const float* f; int o, w, hw; float s; };

__device__ inline Lvl level_of(int a, const float* f0, const float* f1, const float* f2){
  Lvl L;
  if (a < 6400)      { L.f = f0; L.o = a;        L.w = 80; L.hw = 6400; L.s = 8.f;  }
  else if (a < 8000) { L.f = f1; L.o = a - 6400; L.w = 40; L.hw = 1600; L.s = 16.f; }
  else               { L.f = f2; L.o = a - 8000; L.w = 20; L.hw = 400;  L.s = 32.f; }
  return L;
}

__device__ inline float frcp(float x){ return __builtin_amdgcn_rcpf(x); }

// fast atan, |err| < ~2e-6
__device__ inline float fast_atan(float x){
  float ax = fabsf(x);
  bool big = ax > 1.f;
  float z = big ? frcp(ax) : ax;
  float z2 = z * z;
  float p = fmaf(z2, -0.0117212f, 0.0526533f);
  p = fmaf(z2, p, -0.1164329f);
  p = fmaf(z2, p, 0.1935435f);
  p = fmaf(z2, p, -0.3326235f);
  p = fmaf(z2, p, 0.9999773f);
  float r = z * p;
  r = big ? 1.57079632679f - r : r;
  return copysignf(r, x);
}

__device__ inline float ciou_f(float b1x1,float b1y1,float b1x2,float b1y2,
                               float b2x1,float b2y1,float b2x2,float b2y2){
  const float eps = 1e-7f;
  float w1 = b1x2 - b1x1, h1 = b1y2 - b1y1 + eps;
  float w2 = b2x2 - b2x1, h2 = b2y2 - b2y1 + eps;
  float iw = fmaxf(fminf(b1x2, b2x2) - fmaxf(b1x1, b2x1), 0.f);
  float ih = fmaxf(fminf(b1y2, b2y2) - fmaxf(b1y1, b2y1), 0.f);
  float inter = iw * ih;
  float uni = w1 * h1 + w2 * h2 - inter + eps;
  float iou = inter * frcp(uni);
  float cw = fmaxf(b1x2, b2x2) - fminf(b1x1, b2x1);
  float ch = fmaxf(b1y2, b2y2) - fminf(b1y1, b2y1);
  float c2 = cw * cw + ch * ch + eps;
  float dx = b2x1 + b2x2 - b1x1 - b1x2;
  float dy = b2y1 + b2y2 - b1y1 - b1y2;
  float rho2 = (dx * dx + dy * dy) * 0.25f;
  float r1 = w1 * frcp(h1), r2 = w2 * frcp(h2);
  float dat = fast_atan((r2 - r1) * frcp(fmaf(r1, r2, 1.f)));
  float v = VCOEF * dat * dat;
  float alpha = v * frcp(v - iou + (1.0f + eps));
  return iou - (rho2 * frcp(c2) + v * alpha);
}

__device__ inline unsigned long long shfl_xor_u64(unsigned long long v, int mask){
  int lo = __shfl_xor((int)(unsigned)(v & 0xFFFFFFFFull), mask);
  int hi = __shfl_xor((int)(unsigned)(v >> 32), mask);
  return ((unsigned long long)(unsigned)hi << 32) | (unsigned)lo;
}

// ---------------- kernel 1: preprocess targets ----------------
__global__ void k_prep(const float* __restrict__ tgt, float* __restrict__ out5,
                       float* __restrict__ gtbox, int* __restrict__ gtlab,
                       float* __restrict__ gtmask, int* __restrict__ pa_i,
                       int* __restrict__ po_i, int* __restrict__ count,
                       double* __restrict__ acc){
  int t = threadIdx.x; // 0..639
  for (int i = t; i < BM * 5; i += 640) out5[i] = 0.f;
  if (t < 8) acc[t] = 0.0;
  if (t == 0) *count = 0;
  pa_i[t] = 0; po_i[t] = 0;
  __syncthreads();
  {
    int img = (int)tgt[t * 6 + 0];
    int j = t;
    while (j > 0 && (int)tgt[(j - 1) * 6 + 0] == img) j--;
    int pos = t - j;
    if (img >= 0 && img < BB && pos < MM){
      for (int k = 0; k < 5; k++)
        out5[(img * MM + pos) * 5 + k] = tgt[t * 6 + 1 + k];
    }
  }
  __syncthreads();
  {
    float lab = out5[t * 5 + 0];
    float cx = out5[t * 5 + 1] * 640.f;
    float cy = out5[t * 5 + 2] * 640.f;
    float w  = out5[t * 5 + 3] * 640.f;
    float h  = out5[t * 5 + 4] * 640.f;
    float x1 = cx - w * 0.5f, y1 = cy - h * 0.5f;
    float x2 = cx + w * 0.5f, y2 = cy + h * 0.5f;
    gtbox[t * 4 + 0] = x1; gtbox[t * 4 + 1] = y1;
    gtbox[t * 4 + 2] = x2; gtbox[t * 4 + 3] = y2;
    gtlab[t] = (int)lab;
    gtmask[t] = ((x1 + y1 + x2 + y2) > 0.f) ? 1.f : 0.f;
  }
}

// ---------------- kernel 2a: cls softplus streaming sum ----------------
__device__ inline float softplus4(float4 v){
  float s = fmaxf(v.x, 0.f) + __logf(1.f + __expf(-fabsf(v.x)));
  s += fmaxf(v.y, 0.f) + __logf(1.f + __expf(-fabsf(v.y)));
  s += fmaxf(v.z, 0.f) + __logf(1.f + __expf(-fabsf(v.z)));
  s += fmaxf(v.w, 0.f) + __logf(1.f + __expf(-fabsf(v.w)));
  return s;
}

__global__ __launch_bounds__(256) void k_cls(
    const float* __restrict__ f0, const float* __restrict__ f1,
    const float* __restrict__ f2, double* __restrict__ acc){
  int gtid = blockIdx.x * 256 + threadIdx.x;
  int gsz = gridDim.x * 256;
  float sp = 0.f;
  { // feat0: per image, 80*6400 floats at offset 64*6400 in a 144*6400 slab
    constexpr int PER_B = 80 * 6400 / 4;
    for (int i = gtid; i < BB * PER_B; i += gsz){
      int b = i / PER_B, r = i - b * PER_B;
      const float4* p = (const float4*)(f0 + (size_t)b * NOC * 6400 + 64 * 6400);
      sp += softplus4(p[r]);
    }
  }
  { // feat1
    constexpr int PER_B = 80 * 1600 / 4;
    for (int i = gtid; i < BB * PER_B; i += gsz){
      int b = i / PER_B, r = i - b * PER_B;
      const float4* p = (const float4*)(f1 + (size_t)b * NOC * 1600 + 64 * 1600);
      sp += softplus4(p[r]);
    }
  }
  { // feat2
    constexpr int PER_B = 80 * 400 / 4;
    for (int i = gtid; i < BB * PER_B; i += gsz){
      int b = i / PER_B, r = i - b * PER_B;
      const float4* p = (const float4*)(f2 + (size_t)b * NOC * 400 + 64 * 400);
      sp += softplus4(p[r]);
    }
  }
  for (int off = 32; off; off >>= 1) sp += __shfl_down(sp, off);
  __shared__ float red[4];
  int wid = threadIdx.x >> 6, lid = threadIdx.x & 63;
  if (lid == 0) red[wid] = sp;
  __syncthreads();
  if (threadIdx.x == 0)
    atomicAdd(&acc[4], (double)(red[0] + red[1] + red[2] + red[3]));
}

// ---------------- kernel 2b: DFL decode (template per level) ----------------
template<int HW, int W, int AOFF>
__device__ inline void dfl_one(const float* __restrict__ f, int b, int o,
                               float4* __restrict__ pbox, float4* __restrict__ lse,
                               unsigned* __restrict__ mpos){
  int a = AOFF + o;
  mpos[(size_t)b * AT + a] = 0u;
  const float* base = f + (size_t)b * NOC * HW + o;
  int iy = o / W;                        // compile-time W -> magic mul
  float ax = (float)(o - iy * W) + 0.5f;
  float ay = (float)iy + 0.5f;
  float x[4][16];
#pragma unroll
  for (int s = 0; s < 4; s++)
#pragma unroll
    for (int j = 0; j < 16; j++)
      x[s][j] = base[(size_t)(s * 16 + j) * HW];
  float d[4], ls[4];
#pragma unroll
  for (int s = 0; s < 4; s++){
    float mx = x[s][0];
#pragma unroll
    for (int j = 1; j < 16; j++) mx = fmaxf(mx, x[s][j]);
    float sm = 0.f, dt = 0.f;
#pragma unroll
    for (int j = 0; j < 16; j++){
      float e = __expf(x[s][j] - mx);
      sm += e; dt = fmaf(e, (float)j, dt);
    }
    d[s] = dt * frcp(sm);
    ls[s] = mx + __logf(sm);
  }
  int idx = b * AT + a;
  pbox[idx] = make_float4(ax - d[0], ay - d[1], ax + d[2], ay + d[3]);
  lse[idx]  = make_float4(ls[0], ls[1], ls[2], ls[3]);
}

__global__ __launch_bounds__(256, 4) void k_dfl(
    const float* __restrict__ f0, const float* __restrict__ f1,
    const float* __restrict__ f2,
    float4* __restrict__ pbox, float4* __restrict__ lse,
    unsigned* __restrict__ mpos){
  int blk = blockIdx.x;
  int b = blk & 31, tile = blk >> 5;
  int tid = threadIdx.x;
  if (tile < 25){
    int o = tile * 256 + tid;
    dfl_one<6400, 80, 0>(f0, b, o, pbox, lse, mpos);
  } else if (tile < 32){
    int o = (tile - 25) * 256 + tid;
    if (o < 1600) dfl_one<1600, 40, 6400>(f1, b, o, pbox, lse, mpos);
  } else {
    int o = (tile - 32) * 256 + tid;
    if (o < 400) dfl_one<400, 20, 8000>(f2, b, o, pbox, lse, mpos);
  }
}

// ---------------- kernel 3: candidate LDS table + 10x block argmax + scatter ----------------
__global__ __launch_bounds__(256) void k_align(
    const float* __restrict__ f0, const float* __restrict__ f1,
    const float* __restrict__ f2, const float4* __restrict__ pbox,
    const float* __restrict__ gtbox, const int* __restrict__ gtlab,
    const float* __restrict__ gtmask,
    unsigned* __restrict__ mpos, unsigned* __restrict__ list,
    int* __restrict__ count){
  int pair = blockIdx.x;
  int b = pair / MM, m = pair % MM;
  if (gtmask[pair] <= 0.f) return;  // block-uniform exit
  int tid = threadIdx.x;
  float gx1 = gtbox[pair * 4 + 0], gy1 = gtbox[pair * 4 + 1];
  float gx2 = gtbox[pair * 4 + 2], gy2 = gtbox[pair * 4 + 3];
  int lab = gtlab[pair];
  __shared__ float s_val[NSLOT];
  __shared__ int   s_anc[NSLOT];
  __shared__ unsigned long long s_red[4];
  __shared__ int   s_win[TK];
  int base = 0;

#define PROC_LEVEL(FPTR, W, HW, AOFF, S)                                      \
  {                                                                           \
    const float s_ = (S); const float inv_ = 1.f / (S);                       \
    int x0 = max(0, (int)floorf(gx1 * inv_ - 0.5f));                          \
    int x1 = min((W) - 1, (int)ceilf(gx2 * inv_ - 0.5f));                     \
    int y0 = max(0, (int)floorf(gy1 * inv_ - 0.5f));                          \
    int y1 = min((W) - 1, (int)ceilf(gy2 * inv_ - 0.5f));                     \
    int nxx = x1 - x0 + 1, nyy = y1 - y0 + 1;                                 \
    if (nxx > 0 && nyy > 0){                                                  \
      int ntot = nxx * nyy;                                                   \
      unsigned magic = 0xFFFFFFFFu / (unsigned)nxx + 1u;                      \
      const float* clsrow = (FPTR) + (size_t)b * NOC * (HW)                   \
                            + (size_t)(4 * RM + lab) * (HW);                  \
      for (int t = tid; t < ntot; t += 256){                                  \
        int slot = base + t;                                                  \
        if (slot >= NSLOT) break;                                             \
        int iy = (int)(((unsigned long long)(unsigned)t * magic) >> 32);      \
        int ix = t - iy * nxx + x0;                                           \
        iy += y0;                                                             \
        float ax = ((float)ix + 0.5f) * s_;                                   \
        float ay = ((float)iy + 0.5f) * s_;                                   \
        float mn = fminf(fminf(ax - gx1, ay - gy1),                           \
                         fminf(gx2 - ax, gy2 - ay));                          \
        int o = iy * (W) + ix;                                                \
        int a = (AOFF) + o;                                                   \
        float aln = -1.f;                                                     \
        if (mn > EPS_A){                                                      \
          float4 pb = pbox[b * AT + a];                                       \
          float c = ciou_f(gx1, gy1, gx2, gy2,                                \
                           pb.x * s_, pb.y * s_, pb.z * s_, pb.w * s_);       \
          float ovl = fmaxf(c, 0.f);                                          \
          if (ovl > 0.f){                                                     \
            float xv = clsrow[o];                                             \
            float sc = frcp(1.f + __expf(-xv));                               \
            float o2 = ovl * ovl;                                             \
            aln = sqrtf(sc) * (o2 * o2 * o2);                                 \
          }                                                                   \
        }                                                                     \
        s_val[slot] = aln;                                                    \
        s_anc[slot] = a;                                                      \
      }                                                                       \
      base += ntot;                                                           \
    }                                                                         \
  }

  PROC_LEVEL(f0, 80, 6400, 0, 8.f)
  PROC_LEVEL(f1, 40, 1600, 6400, 16.f)
  PROC_LEVEL(f2, 20, 400, 8000, 32.f)
#undef PROC_LEVEL

  __syncthreads();
  int total = min(base, NSLOT);
  int wid = tid >> 6, lid = tid & 63;
  // 10 rounds of block-wide argmax (value desc, slot asc == anchor asc)
  for (int r = 0; r < TK; r++){
    unsigned long long key = 0ULL;
    for (int i = tid; i < total; i += 256){
      float v = s_val[i];
      if (v > 0.f){
        unsigned long long k2 =
            ((unsigned long long)__float_as_uint(v) << 32) |
            (unsigned long long)(0xFFFFFFFFu - (unsigned)i);
        key = key > k2 ? key : k2;
      }
    }
    for (int xm = 1; xm < 64; xm <<= 1){
      unsigned long long o = shfl_xor_u64(key, xm);
      key = key > o ? key : o;
    }
    if (lid == 0) s_red[wid] = key;
    __syncthreads();
    if (tid == 0){
      unsigned long long k = s_red[0];
      k = k > s_red[1] ? k : s_red[1];
      k = k > s_red[2] ? k : s_red[2];
      k = k > s_red[3] ? k : s_red[3];
      if (k){
        int slot = (int)(0xFFFFFFFFu - (unsigned)(k & 0xFFFFFFFFull));
        s_win[r] = s_anc[slot];
        s_val[slot] = -1.f;
      } else s_win[r] = -1;
    }
    __syncthreads();
  }
  if (tid == 0){
    for (int k = 0; k < TK; k++){
      int a = s_win[k];
      if (a >= 0){
        unsigned old = atomicOr(&mpos[(size_t)b * AT + a], 1u << m);
        if (old == 0){
          int i = atomicAdd(count, 1);
          list[i] = ((unsigned)b << 14) | (unsigned)a;
        }
      }
    }
  }
}

// ---------------- kernel 4: resolve multi-claims, pos maxima (compact list) ----------------
__global__ __launch_bounds__(256) void k_resolve(
    const float* __restrict__ f0, const float* __restrict__ f1,
    const float* __restrict__ f2, const float4* __restrict__ pbox,
    const float* __restrict__ gtbox, const int* __restrict__ gtlab,
    const float* __restrict__ gtmask, const unsigned* __restrict__ mpos,
    const unsigned* __restrict__ list, const int* __restrict__ count,
    unsigned* __restrict__ list_m, float* __restrict__ list_aln,
    int* __restrict__ pa_i, int* __restrict__ po_i){
  int i = blockIdx.x * 256 + threadIdx.x;
  if (i >= *count) return;
  unsigned pk = list[i];
  int b = pk >> 14, a = pk & 0x3FFF;
  unsigned bits = mpos[(size_t)b * AT + a];
  Lvl L = level_of(a, f0, f1, f2);
  float ax = ((float)(L.o % L.w) + 0.5f) * L.s;
  float ay = ((float)(L.o / L.w) + 0.5f) * L.s;
  float4 pb = pbox[b * AT + a];
  float px1 = pb.x * L.s, py1 = pb.y * L.s, px2 = pb.z * L.s, py2 = pb.w * L.s;
  int m; float ovl;
  if (__popc(bits) > 1){
    float best = -1.f; int bm = 0;
    for (int mm = 0; mm < MM; mm++){
      float v = 0.f;
      if (gtmask[b * MM + mm] > 0.f){
        float x1 = gtbox[(b * MM + mm) * 4 + 0], y1 = gtbox[(b * MM + mm) * 4 + 1];
        float x2 = gtbox[(b * MM + mm) * 4 + 2], y2 = gtbox[(b * MM + mm) * 4 + 3];
        float mn = fminf(fminf(ax - x1, ay - y1), fminf(x2 - ax, y2 - ay));
        if (mn > EPS_A)
          v = fmaxf(ciou_f(x1, y1, x2, y2, px1, py1, px2, py2), 0.f);
      }
      if (v > best){ best = v; bm = mm; }
    }
    m = bm; ovl = fmaxf(best, 0.f);
  } else {
    m = __ffs(bits) - 1;
    float x1 = gtbox[(b * MM + m) * 4 + 0], y1 = gtbox[(b * MM + m) * 4 + 1];
    float x2 = gtbox[(b * MM + m) * 4 + 2], y2 = gtbox[(b * MM + m) * 4 + 3];
    ovl = fmaxf(ciou_f(x1, y1, x2, y2, px1, py1, px2, py2), 0.f);
  }
  int lab = gtlab[b * MM + m];
  float xv = L.f[(size_t)b * NOC * L.hw + (size_t)(4 * RM + lab) * L.hw + L.o];
  float sc = frcp(1.f + __expf(-xv));
  float o2 = ovl * ovl;
  float aln = sqrtf(sc) * (o2 * o2 * o2);
  list_m[i] = (unsigned)m;
  list_aln[i] = aln;
  atomicMax(&pa_i[b * MM + m], __float_as_int(aln));
  atomicMax(&po_i[b * MM + m], __float_as_int(ovl));
}

// ---------------- kernel 5: per-positive losses (compact list) ----------------
__global__ __launch_bounds__(256) void k_final(
    const float* __restrict__ f0, const float* __restrict__ f1,
    const float* __restrict__ f2,
    const float4* __restrict__ pbox, const float4* __restrict__ lse,
    const float* __restrict__ gtbox, const int* __restrict__ gtlab,
    const int* __restrict__ pa_i, const int* __restrict__ po_i,
    const unsigned* __restrict__ list, const unsigned* __restrict__ list_m,
    const float* __restrict__ list_aln, const int* __restrict__ count,
    double* __restrict__ acc){
  int i = blockIdx.x * 256 + threadIdx.x;
  float w_ = 0.f, clsp = 0.f, boxp = 0.f, dflp = 0.f;
  if (i < *count){
    unsigned pk = list[i];
    int b = pk >> 14, a = pk & 0x3FFF;
    int m = (int)list_m[i];
    float aln = list_aln[i];
    float pa = __int_as_float(pa_i[b * MM + m]);
    float po = __int_as_float(po_i[b * MM + m]);
    w_ = aln * po * frcp(pa + EPS_A);
    Lvl L = level_of(a, f0, f1, f2);
    const float* base = L.f + (size_t)b * NOC * L.hw + L.o;
    float ax = (float)(L.o % L.w) + 0.5f;
    float ay = (float)(L.o / L.w) + 0.5f;
    float inv_s = frcp(L.s);
    float tx1 = gtbox[(b * MM + m) * 4 + 0] * inv_s, ty1 = gtbox[(b * MM + m) * 4 + 1] * inv_s;
    float tx2 = gtbox[(b * MM + m) * 4 + 2] * inv_s, ty2 = gtbox[(b * MM + m) * 4 + 3] * inv_s;
    float4 pb = pbox[b * AT + a];
    float iou = ciou_f(pb.x, pb.y, pb.z, pb.w, tx1, ty1, tx2, ty2);
    boxp = (1.f - iou) * w_;
    float4 L4 = lse[b * AT + a];
    float lsv[4] = { L4.x, L4.y, L4.z, L4.w };
    float tv[4] = { ax - tx1, ay - ty1, tx2 - ax, ty2 - ay };
    float dfl = 0.f;
#pragma unroll
    for (int s4 = 0; s4 < 4; s4++){
      float t = fminf(fmaxf(tv[s4], 0.f), (float)(RM - 1) - 0.01f);
      int tl = (int)t;
      float wl = (float)(tl + 1) - t;
      float xl = base[(size_t)(s4 * RM + tl) * L.hw];
      float xr = base[(size_t)(s4 * RM + tl + 1) * L.hw];
      dfl += (lsv[s4] - xl) * wl + (lsv[s4] - xr) * (1.f - wl);
    }
    dflp = dfl * 0.25f * w_;
    int lab = gtlab[b * MM + m];
    clsp = base[(size_t)(4 * RM + lab) * L.hw] * w_;
  }
  __shared__ float red[4][4];
  float vals[4] = { w_, clsp, boxp, dflp };
  int wid = threadIdx.x >> 6, lid = threadIdx.x & 63;
#pragma unroll
  for (int j = 0; j < 4; j++){
    float v = vals[j];
    for (int off = 32; off; off >>= 1) v += __shfl_down(v, off);
    if (lid == 0) red[wid][j] = v;
  }
  __syncthreads();
  if (threadIdx.x == 0){
    float t0 = 0.f, t1 = 0.f, t2 = 0.f, t3 = 0.f;
    for (int w2 = 0; w2 < 4; w2++){
      t0 += red[w2][0]; t1 += red[w2][1]; t2 += red[w2][2]; t3 += red[w2][3];
    }
    atomicAdd(&acc[0], (double)t0);
    atomicAdd(&acc[1], (double)t1);
    atomicAdd(&acc[2], (double)t2);
    atomicAdd(&acc[3], (double)t3);
  }
}

// ---------------- kernel 6: finalize ----------------
__global__ void k_out(const double* __restrict__ acc, float* __restrict__ out){
  if (threadIdx.x == 0 && blockIdx.x == 0){
    double tss = acc[0] > 1.0 ? acc[0] : 1.0;
    double loss_box = acc[2] / tss;
    double loss_cls = (acc[4] - acc[1]) / tss;
    double loss_dfl = acc[3] / tss;
    float l0 = (float)(loss_box * 7.5);
    float l1 = (float)(loss_cls * 0.5);
    float l2 = (float)(loss_dfl * 1.5);
    out[0] = (l0 + l1 + l2) * 32.f;
    out[1] = l0;
    out[2] = l1;
    out[3] = l2;
  }
}

extern "C" void kernel_launch(void* const* d_in, const int* in_sizes, int n_in,
                              void* d_out, int out_size, void* d_ws, size_t ws_size,
                              hipStream_t stream) {
  const float* f0 = (const float*)d_in[0];
  const float* f1 = (const float*)d_in[1];
  const float* f2 = (const float*)d_in[2];
  const float* tg = (const float*)d_in[3];
  float* out = (float*)d_out;

  char* w = (char*)d_ws;
  size_t off = 0;
  auto alloc = [&](size_t bytes) -> void* {
    void* p = w + off;
    off += (bytes + 255) & ~(size_t)255;
    return p;
  };
  float4*   pbox    = (float4*)  alloc((size_t)BA * 16);
  float4*   lse     = (float4*)  alloc((size_t)BA * 16);
  float*    gtbox   = (float*)   alloc((size_t)BM * 16);
  int*      gtlab   = (int*)     alloc((size_t)BM * 4);
  float*    gtmask  = (float*)   alloc((size_t)BM * 4);
  float*    out5    = (float*)   alloc((size_t)BM * 20);
  unsigned* mpos    = (unsigned*)alloc((size_t)BA * 4);   // zeroed by k_dfl
  int*      count   = (int*)     alloc(4);                // zeroed by k_prep
  unsigned* list    = (unsigned*)alloc((size_t)MAXPOS * 4);
  unsigned* list_m  = (unsigned*)alloc((size_t)MAXPOS * 4);
  float*    list_aln= (float*)   alloc((size_t)MAXPOS * 4);
  int*      pa      = (int*)     alloc((size_t)BM * 4);
  int*      po      = (int*)     alloc((size_t)BM * 4);
  double*   acc     = (double*)  alloc(8 * 8);

  k_prep<<<1, 640, 0, stream>>>(tg, out5, gtbox, gtlab, gtmask, pa, po, count, acc);
  k_cls<<<2048, 256, 0, stream>>>(f0, f1, f2, acc);
  k_dfl<<<34 * 32, 256, 0, stream>>>(f0, f1, f2, pbox, lse, mpos);
  k_align<<<BM, 256, 0, stream>>>(f0, f1, f2, pbox, gtbox, gtlab, gtmask,
                                  mpos, list, count);
  k_resolve<<<MAXPOS / 256, 256, 0, stream>>>(f0, f1, f2, pbox, gtbox, gtlab, gtmask,
                                              mpos, list, count, list_m, list_aln, pa, po);
  k_final<<<MAXPOS / 256, 256, 0, stream>>>(f0, f1, f2, pbox, lse, gtbox, gtlab,
                                            pa, po, list, list_m, list_aln, count, acc);
  k_out<<<1, 64, 0, stream>>>(acc, out);
}

// Round 6
// 319.766 us; speedup vs baseline: 1.0365x; 1.0352x over previous
//
#include <hip/hip_runtime.h>
#include <math.h>

// ---- static config (mirrors reference) ----
constexpr int BB  = 32;     // batch
constexpr int MM  = 20;     // max gt per image
constexpr int NCC = 80;     // classes
constexpr int RM  = 16;     // reg_max
constexpr int NOC = 144;    // channels per head
constexpr int AT  = 8400;   // anchors
constexpr int TK  = 10;     // topk
constexpr int BA  = BB * AT;  // 268800
constexpr int BM  = BB * MM;  // 640
constexpr int MAXPOS = BM * TK; // 6400 max positive anchors
constexpr int NSLOT = 1024;     // max candidates per gt
constexpr int NTILE = 100 + 25 + 7;  // 64-anchor tiles per image (f0,f1,f2)
constexpr float EPS_A = 1e-9f;
constexpr float VCOEF = 0.40528473456935108577551785283891f; // 4/pi^2

struct Lvl { const float* f; int o, w, hw; float s; };

__device__ inline Lvl level_of(int a, const float* f0, const float* f1, const float* f2){
  Lvl L;
  if (a < 6400)      { L.f = f0; L.o = a;        L.w = 80; L.hw = 6400; L.s = 8.f;  }
  else if (a < 8000) { L.f = f1; L.o = a - 6400; L.w = 40; L.hw = 1600; L.s = 16.f; }
  else               { L.f = f2; L.o = a - 8000; L.w = 20; L.hw = 400;  L.s = 32.f; }
  return L;
}

__device__ inline float frcp(float x){ return __builtin_amdgcn_rcpf(x); }

// fast atan, |err| < ~2e-6
__device__ inline float fast_atan(float x){
  float ax = fabsf(x);
  bool big = ax > 1.f;
  float z = big ? frcp(ax) : ax;
  float z2 = z * z;
  float p = fmaf(z2, -0.0117212f, 0.0526533f);
  p = fmaf(z2, p, -0.1164329f);
  p = fmaf(z2, p, 0.1935435f);
  p = fmaf(z2, p, -0.3326235f);
  p = fmaf(z2, p, 0.9999773f);
  float r = z * p;
  r = big ? 1.57079632679f - r : r;
  return copysignf(r, x);
}

__device__ inline float ciou_f(float b1x1,float b1y1,float b1x2,float b1y2,
                               float b2x1,float b2y1,float b2x2,float b2y2){
  const float eps = 1e-7f;
  float w1 = b1x2 - b1x1, h1 = b1y2 - b1y1 + eps;
  float w2 = b2x2 - b2x1, h2 = b2y2 - b2y1 + eps;
  float iw = fmaxf(fminf(b1x2, b2x2) - fmaxf(b1x1, b2x1), 0.f);
  float ih = fmaxf(fminf(b1y2, b2y2) - fmaxf(b1y1, b2y1), 0.f);
  float inter = iw * ih;
  float uni = w1 * h1 + w2 * h2 - inter + eps;
  float iou = inter * frcp(uni);
  float cw = fmaxf(b1x2, b2x2) - fminf(b1x1, b2x1);
  float ch = fmaxf(b1y2, b2y2) - fminf(b1y1, b2y1);
  float c2 = cw * cw + ch * ch + eps;
  float dx = b2x1 + b2x2 - b1x1 - b1x2;
  float dy = b2y1 + b2y2 - b1y1 - b1y2;
  float rho2 = (dx * dx + dy * dy) * 0.25f;
  float r1 = w1 * frcp(h1), r2 = w2 * frcp(h2);
  float dat = fast_atan((r2 - r1) * frcp(fmaf(r1, r2, 1.f)));
  float v = VCOEF * dat * dat;
  float alpha = v * frcp(v - iou + (1.0f + eps));
  return iou - (rho2 * frcp(c2) + v * alpha);
}

__device__ inline unsigned long long shfl_xor_u64(unsigned long long v, int mask){
  int lo = __shfl_xor((int)(unsigned)(v & 0xFFFFFFFFull), mask);
  int hi = __shfl_xor((int)(unsigned)(v >> 32), mask);
  return ((unsigned long long)(unsigned)hi << 32) | (unsigned)lo;
}

__device__ inline float softplus4(float4 v){
  float s = fmaxf(v.x, 0.f) + __logf(1.f + __expf(-fabsf(v.x)));
  s += fmaxf(v.y, 0.f) + __logf(1.f + __expf(-fabsf(v.y)));
  s += fmaxf(v.z, 0.f) + __logf(1.f + __expf(-fabsf(v.z)));
  s += fmaxf(v.w, 0.f) + __logf(1.f + __expf(-fabsf(v.w)));
  return s;
}

// ---------------- kernel 1: preprocess targets ----------------
__global__ void k_prep(const float* __restrict__ tgt, float* __restrict__ out5,
                       float* __restrict__ gtbox, int* __restrict__ gtlab,
                       float* __restrict__ gtmask, int* __restrict__ pa_i,
                       int* __restrict__ po_i, int* __restrict__ count,
                       double* __restrict__ acc){
  int t = threadIdx.x; // 0..639
  for (int i = t; i < BM * 5; i += 640) out5[i] = 0.f;
  if (t < 8) acc[t] = 0.0;
  if (t == 0) *count = 0;
  pa_i[t] = 0; po_i[t] = 0;
  __syncthreads();
  {
    int img = (int)tgt[t * 6 + 0];
    int j = t;
    while (j > 0 && (int)tgt[(j - 1) * 6 + 0] == img) j--;
    int pos = t - j;
    if (img >= 0 && img < BB && pos < MM){
      for (int k = 0; k < 5; k++)
        out5[(img * MM + pos) * 5 + k] = tgt[t * 6 + 1 + k];
    }
  }
  __syncthreads();
  {
    float lab = out5[t * 5 + 0];
    float cx = out5[t * 5 + 1] * 640.f;
    float cy = out5[t * 5 + 2] * 640.f;
    float w  = out5[t * 5 + 3] * 640.f;
    float h  = out5[t * 5 + 4] * 640.f;
    float x1 = cx - w * 0.5f, y1 = cy - h * 0.5f;
    float x2 = cx + w * 0.5f, y2 = cy + h * 0.5f;
    gtbox[t * 4 + 0] = x1; gtbox[t * 4 + 1] = y1;
    gtbox[t * 4 + 2] = x2; gtbox[t * 4 + 3] = y2;
    gtlab[t] = (int)lab;
    gtmask[t] = ((x1 + y1 + x2 + y2) > 0.f) ? 1.f : 0.f;
  }
}

// ---------------- kernel 2: fused feature pass ----------------
// One block per (image, 64-anchor tile). Coalesced float4 rows for all 144
// channels; cls softplus inline; DFL transpose through padded LDS; one
// softmax per (anchor,side) thread; writes pbox/lse; zeroes mpos.
template<int HW, int W, int AOFF>
__device__ inline float feat_tile(const float* __restrict__ f, int b, int tile,
                                  float4* __restrict__ pbox, float4* __restrict__ lseg,
                                  unsigned* __restrict__ mpos,
                                  float (*sT)[65], float (*sD)[64], float (*sL)[64]){
  int tid = threadIdx.x;
  int o0 = tile * 64;
  int nA = HW - o0; if (nA > 64) nA = 64;
  const float* base = f + (size_t)b * NOC * HW + o0;
  // cls softplus: 80 ch x nA anchors (5 float4 per thread)
  float sp = 0.f;
  const float* cb = base + (size_t)(4 * RM) * HW;
#pragma unroll
  for (int k = 0; k < 5; k++){
    int idx = k * 256 + tid;          // 0..1279 -> (ch, float4-group)
    int ch = idx >> 4, f4i = idx & 15;
    if (f4i * 4 < nA)
      sp += softplus4(*(const float4*)(cb + (size_t)ch * HW + f4i * 4));
  }
  // dfl: 64 ch x nA anchors -> LDS transpose (4 float4 per thread)
#pragma unroll
  for (int k = 0; k < 4; k++){
    int idx = k * 256 + tid;          // 0..1023
    int ch = idx >> 4, f4i = idx & 15;
    if (f4i * 4 < nA){
      float4 v = *(const float4*)(base + (size_t)ch * HW + f4i * 4);
      sT[ch][f4i * 4 + 0] = v.x; sT[ch][f4i * 4 + 1] = v.y;
      sT[ch][f4i * 4 + 2] = v.z; sT[ch][f4i * 4 + 3] = v.w;
    }
  }
  __syncthreads();
  int anc = tid & 63, side = tid >> 6;
  if (anc < nA){
    float xs[16];
    xs[0] = sT[side * 16][anc];
    float mx = xs[0];
#pragma unroll
    for (int j = 1; j < 16; j++){ xs[j] = sT[side * 16 + j][anc]; mx = fmaxf(mx, xs[j]); }
    float sm = 0.f, dt = 0.f;
#pragma unroll
    for (int j = 0; j < 16; j++){
      float e = __expf(xs[j] - mx);
      sm += e; dt = fmaf(e, (float)j, dt);
    }
    sD[side][anc] = dt * frcp(sm);
    sL[side][anc] = mx + __logf(sm);
  }
  __syncthreads();
  if (tid < nA){
    int o = o0 + tid;
    int iy = o / W;                    // constexpr W -> magic mul
    float ax = (float)(o - iy * W) + 0.5f;
    float ay = (float)iy + 0.5f;
    int gi = b * AT + AOFF + o;
    pbox[gi] = make_float4(ax - sD[0][tid], ay - sD[1][tid],
                           ax + sD[2][tid], ay + sD[3][tid]);
    lseg[gi] = make_float4(sL[0][tid], sL[1][tid], sL[2][tid], sL[3][tid]);
  } else if (tid >= 64 && tid - 64 < nA){
    mpos[(size_t)b * AT + AOFF + o0 + (tid - 64)] = 0u;
  }
  return sp;
}

__global__ __launch_bounds__(256) void k_feat(
    const float* __restrict__ f0, const float* __restrict__ f1,
    const float* __restrict__ f2,
    float4* __restrict__ pbox, float4* __restrict__ lse,
    unsigned* __restrict__ mpos, double* __restrict__ acc){
  __shared__ float sT[64][65];
  __shared__ float sD[4][64];
  __shared__ float sL[4][64];
  int blk = blockIdx.x;
  int b = blk / NTILE, t = blk - b * NTILE;
  float sp;
  if (t < 100)      sp = feat_tile<6400, 80, 0>   (f0, b, t,        pbox, lse, mpos, sT, sD, sL);
  else if (t < 125) sp = feat_tile<1600, 40, 6400>(f1, b, t - 100,  pbox, lse, mpos, sT, sD, sL);
  else              sp = feat_tile< 400, 20, 8000>(f2, b, t - 125,  pbox, lse, mpos, sT, sD, sL);
  for (int off = 32; off; off >>= 1) sp += __shfl_down(sp, off);
  __shared__ float red[4];
  int wid = threadIdx.x >> 6, lid = threadIdx.x & 63;
  if (lid == 0) red[wid] = sp;
  __syncthreads();
  if (threadIdx.x == 0)
    atomicAdd(&acc[4], (double)(red[0] + red[1] + red[2] + red[3]));
}

// ---------------- kernel 3: candidate LDS table + 10x block argmax + scatter ----------------
__global__ __launch_bounds__(256) void k_align(
    const float* __restrict__ f0, const float* __restrict__ f1,
    const float* __restrict__ f2, const float4* __restrict__ pbox,
    const float* __restrict__ gtbox, const int* __restrict__ gtlab,
    const float* __restrict__ gtmask,
    unsigned* __restrict__ mpos, unsigned* __restrict__ list,
    int* __restrict__ count){
  int pair = blockIdx.x;
  int b = pair / MM, m = pair % MM;
  if (gtmask[pair] <= 0.f) return;  // block-uniform exit
  int tid = threadIdx.x;
  float gx1 = gtbox[pair * 4 + 0], gy1 = gtbox[pair * 4 + 1];
  float gx2 = gtbox[pair * 4 + 2], gy2 = gtbox[pair * 4 + 3];
  int lab = gtlab[pair];
  __shared__ float s_val[NSLOT];
  __shared__ int   s_anc[NSLOT];
  __shared__ unsigned long long s_red[4];
  __shared__ int   s_win[TK];
  int base = 0;

#define PROC_LEVEL(FPTR, W, HW, AOFF, S)                                      \
  {                                                                           \
    const float s_ = (S); const float inv_ = 1.f / (S);                       \
    int x0 = max(0, (int)floorf(gx1 * inv_ - 0.5f));                          \
    int x1 = min((W) - 1, (int)ceilf(gx2 * inv_ - 0.5f));                     \
    int y0 = max(0, (int)floorf(gy1 * inv_ - 0.5f));                          \
    int y1 = min((W) - 1, (int)ceilf(gy2 * inv_ - 0.5f));                     \
    int nxx = x1 - x0 + 1, nyy = y1 - y0 + 1;                                 \
    if (nxx > 0 && nyy > 0){                                                  \
      int ntot = nxx * nyy;                                                   \
      unsigned magic = 0xFFFFFFFFu / (unsigned)nxx + 1u;                      \
      const float* clsrow = (FPTR) + (size_t)b * NOC * (HW)                   \
                            + (size_t)(4 * RM + lab) * (HW);                  \
      for (int t = tid; t < ntot; t += 256){                                  \
        int slot = base + t;                                                  \
        if (slot >= NSLOT) break;                                             \
        int iy = (int)(((unsigned long long)(unsigned)t * magic) >> 32);      \
        int ix = t - iy * nxx + x0;                                           \
        iy += y0;                                                             \
        float ax = ((float)ix + 0.5f) * s_;                                   \
        float ay = ((float)iy + 0.5f) * s_;                                   \
        float mn = fminf(fminf(ax - gx1, ay - gy1),                           \
                         fminf(gx2 - ax, gy2 - ay));                          \
        int o = iy * (W) + ix;                                                \
        int a = (AOFF) + o;                                                   \
        float aln = -1.f;                                                     \
        if (mn > EPS_A){                                                      \
          float4 pb = pbox[b * AT + a];                                       \
          float c = ciou_f(gx1, gy1, gx2, gy2,                                \
                           pb.x * s_, pb.y * s_, pb.z * s_, pb.w * s_);       \
          float ovl = fmaxf(c, 0.f);                                          \
          if (ovl > 0.f){                                                     \
            float xv = clsrow[o];                                             \
            float sc = frcp(1.f + __expf(-xv));                               \
            float o2 = ovl * ovl;                                             \
            aln = sqrtf(sc) * (o2 * o2 * o2);                                 \
          }                                                                   \
        }                                                                     \
        s_val[slot] = aln;                                                    \
        s_anc[slot] = a;                                                      \
      }                                                                       \
      base += ntot;                                                           \
    }                                                                         \
  }

  PROC_LEVEL(f0, 80, 6400, 0, 8.f)
  PROC_LEVEL(f1, 40, 1600, 6400, 16.f)
  PROC_LEVEL(f2, 20, 400, 8000, 32.f)
#undef PROC_LEVEL

  __syncthreads();
  int total = min(base, NSLOT);
  int wid = tid >> 6, lid = tid & 63;
  for (int r = 0; r < TK; r++){
    unsigned long long key = 0ULL;
    for (int i = tid; i < total; i += 256){
      float v = s_val[i];
      if (v > 0.f){
        unsigned long long k2 =
            ((unsigned long long)__float_as_uint(v) << 32) |
            (unsigned long long)(0xFFFFFFFFu - (unsigned)i);
        key = key > k2 ? key : k2;
      }
    }
    for (int xm = 1; xm < 64; xm <<= 1){
      unsigned long long o = shfl_xor_u64(key, xm);
      key = key > o ? key : o;
    }
    if (lid == 0) s_red[wid] = key;
    __syncthreads();
    if (tid == 0){
      unsigned long long k = s_red[0];
      k = k > s_red[1] ? k : s_red[1];
      k = k > s_red[2] ? k : s_red[2];
      k = k > s_red[3] ? k : s_red[3];
      if (k){
        int slot = (int)(0xFFFFFFFFu - (unsigned)(k & 0xFFFFFFFFull));
        s_win[r] = s_anc[slot];
        s_val[slot] = -1.f;
      } else s_win[r] = -1;
    }
    __syncthreads();
  }
  if (tid == 0){
    for (int k = 0; k < TK; k++){
      int a = s_win[k];
      if (a >= 0){
        unsigned old = atomicOr(&mpos[(size_t)b * AT + a], 1u << m);
        if (old == 0){
          int i = atomicAdd(count, 1);
          list[i] = ((unsigned)b << 14) | (unsigned)a;
        }
      }
    }
  }
}

// ---------------- kernel 4: resolve multi-claims, pos maxima (compact list) ----------------
__global__ __launch_bounds__(256) void k_resolve(
    const float* __restrict__ f0, const float* __restrict__ f1,
    const float* __restrict__ f2, const float4* __restrict__ pbox,
    const float* __restrict__ gtbox, const int* __restrict__ gtlab,
    const float* __restrict__ gtmask, const unsigned* __restrict__ mpos,
    const unsigned* __restrict__ list, const int* __restrict__ count,
    unsigned* __restrict__ list_m, float* __restrict__ list_aln,
    int* __restrict__ pa_i, int* __restrict__ po_i){
  int i = blockIdx.x * 256 + threadIdx.x;
  if (i >= *count) return;
  unsigned pk = list[i];
  int b = pk >> 14, a = pk & 0x3FFF;
  unsigned bits = mpos[(size_t)b * AT + a];
  Lvl L = level_of(a, f0, f1, f2);
  float ax = ((float)(L.o % L.w) + 0.5f) * L.s;
  float ay = ((float)(L.o / L.w) + 0.5f) * L.s;
  float4 pb = pbox[b * AT + a];
  float px1 = pb.x * L.s, py1 = pb.y * L.s, px2 = pb.z * L.s, py2 = pb.w * L.s;
  int m; float ovl;
  if (__popc(bits) > 1){
    float best = -1.f; int bm = 0;
    for (int mm = 0; mm < MM; mm++){
      float v = 0.f;
      if (gtmask[b * MM + mm] > 0.f){
        float x1 = gtbox[(b * MM + mm) * 4 + 0], y1 = gtbox[(b * MM + mm) * 4 + 1];
        float x2 = gtbox[(b * MM + mm) * 4 + 2], y2 = gtbox[(b * MM + mm) * 4 + 3];
        float mn = fminf(fminf(ax - x1, ay - y1), fminf(x2 - ax, y2 - ay));
        if (mn > EPS_A)
          v = fmaxf(ciou_f(x1, y1, x2, y2, px1, py1, px2, py2), 0.f);
      }
      if (v > best){ best = v; bm = mm; }
    }
    m = bm; ovl = fmaxf(best, 0.f);
  } else {
    m = __ffs(bits) - 1;
    float x1 = gtbox[(b * MM + m) * 4 + 0], y1 = gtbox[(b * MM + m) * 4 + 1];
    float x2 = gtbox[(b * MM + m) * 4 + 2], y2 = gtbox[(b * MM + m) * 4 + 3];
    ovl = fmaxf(ciou_f(x1, y1, x2, y2, px1, py1, px2, py2), 0.f);
  }
  int lab = gtlab[b * MM + m];
  float xv = L.f[(size_t)b * NOC * L.hw + (size_t)(4 * RM + lab) * L.hw + L.o];
  float sc = frcp(1.f + __expf(-xv));
  float o2 = ovl * ovl;
  float aln = sqrtf(sc) * (o2 * o2 * o2);
  list_m[i] = (unsigned)m;
  list_aln[i] = aln;
  atomicMax(&pa_i[b * MM + m], __float_as_int(aln));
  atomicMax(&po_i[b * MM + m], __float_as_int(ovl));
}

// ---------------- kernel 5: per-positive losses (compact list) ----------------
__global__ __launch_bounds__(256) void k_final(
    const float* __restrict__ f0, const float* __restrict__ f1,
    const float* __restrict__ f2,
    const float4* __restrict__ pbox, const float4* __restrict__ lse,
    const float* __restrict__ gtbox, const int* __restrict__ gtlab,
    const int* __restrict__ pa_i, const int* __restrict__ po_i,
    const unsigned* __restrict__ list, const unsigned* __restrict__ list_m,
    const float* __restrict__ list_aln, const int* __restrict__ count,
    double* __restrict__ acc){
  int i = blockIdx.x * 256 + threadIdx.x;
  float w_ = 0.f, clsp = 0.f, boxp = 0.f, dflp = 0.f;
  if (i < *count){
    unsigned pk = list[i];
    int b = pk >> 14, a = pk & 0x3FFF;
    int m = (int)list_m[i];
    float aln = list_aln[i];
    float pa = __int_as_float(pa_i[b * MM + m]);
    float po = __int_as_float(po_i[b * MM + m]);
    w_ = aln * po * frcp(pa + EPS_A);
    Lvl L = level_of(a, f0, f1, f2);
    const float* base = L.f + (size_t)b * NOC * L.hw + L.o;
    float ax = (float)(L.o % L.w) + 0.5f;
    float ay = (float)(L.o / L.w) + 0.5f;
    float inv_s = frcp(L.s);
    float tx1 = gtbox[(b * MM + m) * 4 + 0] * inv_s, ty1 = gtbox[(b * MM + m) * 4 + 1] * inv_s;
    float tx2 = gtbox[(b * MM + m) * 4 + 2] * inv_s, ty2 = gtbox[(b * MM + m) * 4 + 3] * inv_s;
    float4 pb = pbox[b * AT + a];
    float iou = ciou_f(pb.x, pb.y, pb.z, pb.w, tx1, ty1, tx2, ty2);
    boxp = (1.f - iou) * w_;
    float4 L4 = lse[b * AT + a];
    float lsv[4] = { L4.x, L4.y, L4.z, L4.w };
    float tv[4] = { ax - tx1, ay - ty1, tx2 - ax, ty2 - ay };
    float dfl = 0.f;
#pragma unroll
    for (int s4 = 0; s4 < 4; s4++){
      float t = fminf(fmaxf(tv[s4], 0.f), (float)(RM - 1) - 0.01f);
      int tl = (int)t;
      float wl = (float)(tl + 1) - t;
      float xl = base[(size_t)(s4 * RM + tl) * L.hw];
      float xr = base[(size_t)(s4 * RM + tl + 1) * L.hw];
      dfl += (lsv[s4] - xl) * wl + (lsv[s4] - xr) * (1.f - wl);
    }
    dflp = dfl * 0.25f * w_;
    int lab = gtlab[b * MM + m];
    clsp = base[(size_t)(4 * RM + lab) * L.hw] * w_;
  }
  __shared__ float red[4][4];
  float vals[4] = { w_, clsp, boxp, dflp };
  int wid = threadIdx.x >> 6, lid = threadIdx.x & 63;
#pragma unroll
  for (int j = 0; j < 4; j++){
    float v = vals[j];
    for (int off = 32; off; off >>= 1) v += __shfl_down(v, off);
    if (lid == 0) red[wid][j] = v;
  }
  __syncthreads();
  if (threadIdx.x == 0){
    float t0 = 0.f, t1 = 0.f, t2 = 0.f, t3 = 0.f;
    for (int w2 = 0; w2 < 4; w2++){
      t0 += red[w2][0]; t1 += red[w2][1]; t2 += red[w2][2]; t3 += red[w2][3];
    }
    atomicAdd(&acc[0], (double)t0);
    atomicAdd(&acc[1], (double)t1);
    atomicAdd(&acc[2], (double)t2);
    atomicAdd(&acc[3], (double)t3);
  }
}

// ---------------- kernel 6: finalize ----------------
__global__ void k_out(const double* __restrict__ acc, float* __restrict__ out){
  if (threadIdx.x == 0 && blockIdx.x == 0){
    double tss = acc[0] > 1.0 ? acc[0] : 1.0;
    double loss_box = acc[2] / tss;
    double loss_cls = (acc[4] - acc[1]) / tss;
    double loss_dfl = acc[3] / tss;
    float l0 = (float)(loss_box * 7.5);
    float l1 = (float)(loss_cls * 0.5);
    float l2 = (float)(loss_dfl * 1.5);
    out[0] = (l0 + l1 + l2) * 32.f;
    out[1] = l0;
    out[2] = l1;
    out[3] = l2;
  }
}

extern "C" void kernel_launch(void* const* d_in, const int* in_sizes, int n_in,
                              void* d_out, int out_size, void* d_ws, size_t ws_size,
                              hipStream_t stream) {
  const float* f0 = (const float*)d_in[0];
  const float* f1 = (const float*)d_in[1];
  const float* f2 = (const float*)d_in[2];
  const float* tg = (const float*)d_in[3];
  float* out = (float*)d_out;

  char* w = (char*)d_ws;
  size_t off = 0;
  auto alloc = [&](size_t bytes) -> void* {
    void* p = w + off;
    off += (bytes + 255) & ~(size_t)255;
    return p;
  };
  float4*   pbox    = (float4*)  alloc((size_t)BA * 16);
  float4*   lse     = (float4*)  alloc((size_t)BA * 16);
  float*    gtbox   = (float*)   alloc((size_t)BM * 16);
  int*      gtlab   = (int*)     alloc((size_t)BM * 4);
  float*    gtmask  = (float*)   alloc((size_t)BM * 4);
  float*    out5    = (float*)   alloc((size_t)BM * 20);
  unsigned* mpos    = (unsigned*)alloc((size_t)BA * 4);   // zeroed by k_feat
  int*      count   = (int*)     alloc(4);                // zeroed by k_prep
  unsigned* list    = (unsigned*)alloc((size_t)MAXPOS * 4);
  unsigned* list_m  = (unsigned*)alloc((size_t)MAXPOS * 4);
  float*    list_aln= (float*)   alloc((size_t)MAXPOS * 4);
  int*      pa      = (int*)     alloc((size_t)BM * 4);
  int*      po      = (int*)     alloc((size_t)BM * 4);
  double*   acc     = (double*)  alloc(8 * 8);

  k_prep<<<1, 640, 0, stream>>>(tg, out5, gtbox, gtlab, gtmask, pa, po, count, acc);
  k_feat<<<BB * NTILE, 256, 0, stream>>>(f0, f1, f2, pbox, lse, mpos, acc);
  k_align<<<BM, 256, 0, stream>>>(f0, f1, f2, pbox, gtbox, gtlab, gtmask,
                                  mpos, list, count);
  k_resolve<<<MAXPOS / 256, 256, 0, stream>>>(f0, f1, f2, pbox, gtbox, gtlab, gtmask,
                                              mpos, list, count, list_m, list_aln, pa, po);
  k_final<<<MAXPOS / 256, 256, 0, stream>>>(f0, f1, f2, pbox, lse, gtbox, gtlab,
                                            pa, po, list, list_m, list_aln, count, acc);
  k_out<<<1, 64, 0, stream>>>(acc, out);
}

// Round 7
// 253.480 us; speedup vs baseline: 1.3075x; 1.2615x over previous
//
#include <hip/hip_runtime.h>
#include <math.h>

// ---- static config (mirrors reference) ----
constexpr int BB  = 32;     // batch
constexpr int MM  = 20;     // max gt per image
constexpr int NCC = 80;     // classes
constexpr int RM  = 16;     // reg_max
constexpr int NOC = 144;    // channels per head
constexpr int AT  = 8400;   // anchors
constexpr int TK  = 10;     // topk
constexpr int BA  = BB * AT;  // 268800
constexpr int BM  = BB * MM;  // 640
constexpr int MAXPOS = BM * TK; // 6400 topk entries
constexpr int NSLOT = 1024;     // max candidates per gt
constexpr int NTILE = 100 + 25 + 7;  // 64-anchor tiles per image
constexpr float EPS_A = 1e-9f;
constexpr float VCOEF = 0.40528473456935108577551785283891f; // 4/pi^2

struct Lvl { const float* f; int o, w, hw; float s; };

__device__ inline Lvl level_of(int a, const float* f0, const float* f1, const float* f2){
  Lvl L;
  if (a < 6400)      { L.f = f0; L.o = a;        L.w = 80; L.hw = 6400; L.s = 8.f;  }
  else if (a < 8000) { L.f = f1; L.o = a - 6400; L.w = 40; L.hw = 1600; L.s = 16.f; }
  else               { L.f = f2; L.o = a - 8000; L.w = 20; L.hw = 400;  L.s = 32.f; }
  return L;
}

__device__ inline float frcp(float x){ return __builtin_amdgcn_rcpf(x); }

// fast atan, |err| < ~2e-6
__device__ inline float fast_atan(float x){
  float ax = fabsf(x);
  bool big = ax > 1.f;
  float z = big ? frcp(ax) : ax;
  float z2 = z * z;
  float p = fmaf(z2, -0.0117212f, 0.0526533f);
  p = fmaf(z2, p, -0.1164329f);
  p = fmaf(z2, p, 0.1935435f);
  p = fmaf(z2, p, -0.3326235f);
  p = fmaf(z2, p, 0.9999773f);
  float r = z * p;
  r = big ? 1.57079632679f - r : r;
  return copysignf(r, x);
}

__device__ inline float ciou_f(float b1x1,float b1y1,float b1x2,float b1y2,
                               float b2x1,float b2y1,float b2x2,float b2y2){
  const float eps = 1e-7f;
  float w1 = b1x2 - b1x1, h1 = b1y2 - b1y1 + eps;
  float w2 = b2x2 - b2x1, h2 = b2y2 - b2y1 + eps;
  float iw = fmaxf(fminf(b1x2, b2x2) - fmaxf(b1x1, b2x1), 0.f);
  float ih = fmaxf(fminf(b1y2, b2y2) - fmaxf(b1y1, b2y1), 0.f);
  float inter = iw * ih;
  float uni = w1 * h1 + w2 * h2 - inter + eps;
  float iou = inter * frcp(uni);
  float cw = fmaxf(b1x2, b2x2) - fminf(b1x1, b2x1);
  float ch = fmaxf(b1y2, b2y2) - fminf(b1y1, b2y1);
  float c2 = cw * cw + ch * ch + eps;
  float dx = b2x1 + b2x2 - b1x1 - b1x2;
  float dy = b2y1 + b2y2 - b1y1 - b1y2;
  float rho2 = (dx * dx + dy * dy) * 0.25f;
  float r1 = w1 * frcp(h1), r2 = w2 * frcp(h2);
  float dat = fast_atan((r2 - r1) * frcp(fmaf(r1, r2, 1.f)));
  float v = VCOEF * dat * dat;
  float alpha = v * frcp(v - iou + (1.0f + eps));
  return iou - (rho2 * frcp(c2) + v * alpha);
}

__device__ inline unsigned long long shfl_xor_u64(unsigned long long v, int mask){
  int lo = __shfl_xor((int)(unsigned)(v & 0xFFFFFFFFull), mask);
  int hi = __shfl_xor((int)(unsigned)(v >> 32), mask);
  return ((unsigned long long)(unsigned)hi << 32) | (unsigned)lo;
}

__device__ inline float softplus4(float4 v){
  float s = fmaxf(v.x, 0.f) + __logf(1.f + __expf(-fabsf(v.x)));
  s += fmaxf(v.y, 0.f) + __logf(1.f + __expf(-fabsf(v.y)));
  s += fmaxf(v.z, 0.f) + __logf(1.f + __expf(-fabsf(v.z)));
  s += fmaxf(v.w, 0.f) + __logf(1.f + __expf(-fabsf(v.w)));
  return s;
}

// ---------------- kernel 1: preprocess targets ----------------
__global__ void k_prep(const float* __restrict__ tgt, float* __restrict__ out5,
                       float* __restrict__ gtbox, int* __restrict__ gtlab,
                       float* __restrict__ gtmask, int* __restrict__ pa_i,
                       int* __restrict__ po_i, int* __restrict__ topk_arr,
                       double* __restrict__ acc){
  int t = threadIdx.x; // 0..639
  for (int i = t; i < BM * 5; i += 640) out5[i] = 0.f;
  for (int i = t; i < MAXPOS; i += 640) topk_arr[i] = -1;
  if (t < 8) acc[t] = 0.0;
  pa_i[t] = 0; po_i[t] = 0;
  __syncthreads();
  {
    int img = (int)tgt[t * 6 + 0];
    int j = t;
    while (j > 0 && (int)tgt[(j - 1) * 6 + 0] == img) j--;
    int pos = t - j;
    if (img >= 0 && img < BB && pos < MM){
      for (int k = 0; k < 5; k++)
        out5[(img * MM + pos) * 5 + k] = tgt[t * 6 + 1 + k];
    }
  }
  __syncthreads();
  {
    float lab = out5[t * 5 + 0];
    float cx = out5[t * 5 + 1] * 640.f;
    float cy = out5[t * 5 + 2] * 640.f;
    float w  = out5[t * 5 + 3] * 640.f;
    float h  = out5[t * 5 + 4] * 640.f;
    float x1 = cx - w * 0.5f, y1 = cy - h * 0.5f;
    float x2 = cx + w * 0.5f, y2 = cy + h * 0.5f;
    gtbox[t * 4 + 0] = x1; gtbox[t * 4 + 1] = y1;
    gtbox[t * 4 + 2] = x2; gtbox[t * 4 + 3] = y2;
    gtlab[t] = (int)lab;
    gtmask[t] = ((x1 + y1 + x2 + y2) > 0.f) ? 1.f : 0.f;
  }
}

// ---------------- kernel 2: fused feature pass ----------------
template<int HW, int W, int AOFF>
__device__ inline float feat_tile(const float* __restrict__ f, int b, int tile,
                                  float4* __restrict__ pbox, float4* __restrict__ lseg,
                                  unsigned* __restrict__ mpos,
                                  float (*sT)[65], float (*sD)[64], float (*sL)[64]){
  int tid = threadIdx.x;
  int o0 = tile * 64;
  int nA = HW - o0; if (nA > 64) nA = 64;
  const float* base = f + (size_t)b * NOC * HW + o0;
  float sp = 0.f;
  const float* cb = base + (size_t)(4 * RM) * HW;
#pragma unroll
  for (int k = 0; k < 5; k++){
    int idx = k * 256 + tid;
    int ch = idx >> 4, f4i = idx & 15;
    if (f4i * 4 < nA)
      sp += softplus4(*(const float4*)(cb + (size_t)ch * HW + f4i * 4));
  }
#pragma unroll
  for (int k = 0; k < 4; k++){
    int idx = k * 256 + tid;
    int ch = idx >> 4, f4i = idx & 15;
    if (f4i * 4 < nA){
      float4 v = *(const float4*)(base + (size_t)ch * HW + f4i * 4);
      sT[ch][f4i * 4 + 0] = v.x; sT[ch][f4i * 4 + 1] = v.y;
      sT[ch][f4i * 4 + 2] = v.z; sT[ch][f4i * 4 + 3] = v.w;
    }
  }
  __syncthreads();
  int anc = tid & 63, side = tid >> 6;
  if (anc < nA){
    float xs[16];
    xs[0] = sT[side * 16][anc];
    float mx = xs[0];
#pragma unroll
    for (int j = 1; j < 16; j++){ xs[j] = sT[side * 16 + j][anc]; mx = fmaxf(mx, xs[j]); }
    float sm = 0.f, dt = 0.f;
#pragma unroll
    for (int j = 0; j < 16; j++){
      float e = __expf(xs[j] - mx);
      sm += e; dt = fmaf(e, (float)j, dt);
    }
    sD[side][anc] = dt * frcp(sm);
    sL[side][anc] = mx + __logf(sm);
  }
  __syncthreads();
  if (tid < nA){
    int o = o0 + tid;
    int iy = o / W;
    float ax = (float)(o - iy * W) + 0.5f;
    float ay = (float)iy + 0.5f;
    int gi = b * AT + AOFF + o;
    pbox[gi] = make_float4(ax - sD[0][tid], ay - sD[1][tid],
                           ax + sD[2][tid], ay + sD[3][tid]);
    lseg[gi] = make_float4(sL[0][tid], sL[1][tid], sL[2][tid], sL[3][tid]);
  } else if (tid >= 64 && tid - 64 < nA){
    mpos[(size_t)b * AT + AOFF + o0 + (tid - 64)] = 0u;
  }
  return sp;
}

__global__ __launch_bounds__(256) void k_feat(
    const float* __restrict__ f0, const float* __restrict__ f1,
    const float* __restrict__ f2,
    float4* __restrict__ pbox, float4* __restrict__ lse,
    unsigned* __restrict__ mpos, double* __restrict__ acc){
  __shared__ float sT[64][65];
  __shared__ float sD[4][64];
  __shared__ float sL[4][64];
  int blk = blockIdx.x;
  int b = blk / NTILE, t = blk - b * NTILE;
  float sp;
  if (t < 100)      sp = feat_tile<6400, 80, 0>   (f0, b, t,        pbox, lse, mpos, sT, sD, sL);
  else if (t < 125) sp = feat_tile<1600, 40, 6400>(f1, b, t - 100,  pbox, lse, mpos, sT, sD, sL);
  else              sp = feat_tile< 400, 20, 8000>(f2, b, t - 125,  pbox, lse, mpos, sT, sD, sL);
  for (int off = 32; off; off >>= 1) sp += __shfl_down(sp, off);
  __shared__ float red[4];
  int wid = threadIdx.x >> 6, lid = threadIdx.x & 63;
  if (lid == 0) red[wid] = sp;
  __syncthreads();
  if (threadIdx.x == 0)
    atomicAdd(&acc[4], (double)(red[0] + red[1] + red[2] + red[3]));
}

// ---------------- kernel 3: candidate LDS table + 10x block argmax ----------------
// No count/list: top-10 written to fixed slots; atomicOr to distinct mpos words.
__global__ __launch_bounds__(256) void k_align(
    const float* __restrict__ f0, const float* __restrict__ f1,
    const float* __restrict__ f2, const float4* __restrict__ pbox,
    const float* __restrict__ gtbox, const int* __restrict__ gtlab,
    const float* __restrict__ gtmask,
    unsigned* __restrict__ mpos, int* __restrict__ topk_arr){
  int pair = blockIdx.x;
  int b = pair / MM, m = pair % MM;
  if (gtmask[pair] <= 0.f) return;  // topk_arr pre-inited to -1 by k_prep
  int tid = threadIdx.x;
  float gx1 = gtbox[pair * 4 + 0], gy1 = gtbox[pair * 4 + 1];
  float gx2 = gtbox[pair * 4 + 2], gy2 = gtbox[pair * 4 + 3];
  int lab = gtlab[pair];
  __shared__ float s_val[NSLOT];
  __shared__ int   s_anc[NSLOT];
  __shared__ unsigned long long s_red[4];
  __shared__ int   s_win[TK];
  int base = 0;

#define PROC_LEVEL(FPTR, W, HW, AOFF, S)                                      \
  {                                                                           \
    const float s_ = (S); const float inv_ = 1.f / (S);                       \
    int x0 = max(0, (int)floorf(gx1 * inv_ - 0.5f));                          \
    int x1 = min((W) - 1, (int)ceilf(gx2 * inv_ - 0.5f));                     \
    int y0 = max(0, (int)floorf(gy1 * inv_ - 0.5f));                          \
    int y1 = min((W) - 1, (int)ceilf(gy2 * inv_ - 0.5f));                     \
    int nxx = x1 - x0 + 1, nyy = y1 - y0 + 1;                                 \
    if (nxx > 0 && nyy > 0){                                                  \
      int ntot = nxx * nyy;                                                   \
      unsigned magic = 0xFFFFFFFFu / (unsigned)nxx + 1u;                      \
      const float* clsrow = (FPTR) + (size_t)b * NOC * (HW)                   \
                            + (size_t)(4 * RM + lab) * (HW);                  \
      for (int t = tid; t < ntot; t += 256){                                  \
        int slot = base + t;                                                  \
        if (slot >= NSLOT) break;                                             \
        int iy = (int)(((unsigned long long)(unsigned)t * magic) >> 32);      \
        int ix = t - iy * nxx + x0;                                           \
        iy += y0;                                                             \
        float ax = ((float)ix + 0.5f) * s_;                                   \
        float ay = ((float)iy + 0.5f) * s_;                                   \
        float mn = fminf(fminf(ax - gx1, ay - gy1),                           \
                         fminf(gx2 - ax, gy2 - ay));                          \
        int o = iy * (W) + ix;                                                \
        int a = (AOFF) + o;                                                   \
        float aln = -1.f;                                                     \
        if (mn > EPS_A){                                                      \
          float4 pb = pbox[b * AT + a];                                       \
          float c = ciou_f(gx1, gy1, gx2, gy2,                                \
                           pb.x * s_, pb.y * s_, pb.z * s_, pb.w * s_);       \
          float ovl = fmaxf(c, 0.f);                                          \
          if (ovl > 0.f){                                                     \
            float xv = clsrow[o];                                             \
            float sc = frcp(1.f + __expf(-xv));                               \
            float o2 = ovl * ovl;                                             \
            aln = sqrtf(sc) * (o2 * o2 * o2);                                 \
          }                                                                   \
        }                                                                     \
        s_val[slot] = aln;                                                    \
        s_anc[slot] = a;                                                      \
      }                                                                       \
      base += ntot;                                                           \
    }                                                                         \
  }

  PROC_LEVEL(f0, 80, 6400, 0, 8.f)
  PROC_LEVEL(f1, 40, 1600, 6400, 16.f)
  PROC_LEVEL(f2, 20, 400, 8000, 32.f)
#undef PROC_LEVEL

  __syncthreads();
  int total = min(base, NSLOT);
  int wid = tid >> 6, lid = tid & 63;
  for (int r = 0; r < TK; r++){
    unsigned long long key = 0ULL;
    for (int i = tid; i < total; i += 256){
      float v = s_val[i];
      if (v > 0.f){
        unsigned long long k2 =
            ((unsigned long long)__float_as_uint(v) << 32) |
            (unsigned long long)(0xFFFFFFFFu - (unsigned)i);
        key = key > k2 ? key : k2;
      }
    }
    for (int xm = 1; xm < 64; xm <<= 1){
      unsigned long long o = shfl_xor_u64(key, xm);
      key = key > o ? key : o;
    }
    if (lid == 0) s_red[wid] = key;
    __syncthreads();
    if (tid == 0){
      unsigned long long k = s_red[0];
      k = k > s_red[1] ? k : s_red[1];
      k = k > s_red[2] ? k : s_red[2];
      k = k > s_red[3] ? k : s_red[3];
      if (k){
        int slot = (int)(0xFFFFFFFFu - (unsigned)(k & 0xFFFFFFFFull));
        s_win[r] = s_anc[slot];
        s_val[slot] = -1.f;
      } else s_win[r] = -1;
    }
    __syncthreads();
  }
  if (tid < TK){
    int a = s_win[tid];
    topk_arr[pair * TK + tid] = a;
    if (a >= 0) atomicOr(&mpos[(size_t)b * AT + a], 1u << m);
  }
}

// ---------------- kernel 4: resolve multi-claims, pos maxima ----------------
// one thread per (pair,k) topk entry; dedup per anchor via lowest-set-bit rule
__global__ __launch_bounds__(256) void k_resolve(
    const float* __restrict__ f0, const float* __restrict__ f1,
    const float* __restrict__ f2, const float4* __restrict__ pbox,
    const float* __restrict__ gtbox, const int* __restrict__ gtlab,
    const float* __restrict__ gtmask, const unsigned* __restrict__ mpos,
    const int* __restrict__ topk_arr,
    unsigned char* __restrict__ resm, float* __restrict__ resaln,
    int* __restrict__ pa_i, int* __restrict__ po_i){
  int i = blockIdx.x * 256 + threadIdx.x;  // 0..MAXPOS-1
  int a = topk_arr[i];
  if (a < 0) return;
  int pair = i / TK;
  int b = pair / MM, m = pair % MM;
  unsigned bits = mpos[(size_t)b * AT + a];
  if (m != __ffs(bits) - 1) return;        // one thread per positive anchor
  Lvl L = level_of(a, f0, f1, f2);
  float ax = ((float)(L.o % L.w) + 0.5f) * L.s;
  float ay = ((float)(L.o / L.w) + 0.5f) * L.s;
  float4 pb = pbox[b * AT + a];
  float px1 = pb.x * L.s, py1 = pb.y * L.s, px2 = pb.z * L.s, py2 = pb.w * L.s;
  int mr; float ovl;
  if (__popc(bits) > 1){
    float best = -1.f; int bm = 0;
    for (int mm = 0; mm < MM; mm++){
      float v = 0.f;
      if (gtmask[b * MM + mm] > 0.f){
        float x1 = gtbox[(b * MM + mm) * 4 + 0], y1 = gtbox[(b * MM + mm) * 4 + 1];
        float x2 = gtbox[(b * MM + mm) * 4 + 2], y2 = gtbox[(b * MM + mm) * 4 + 3];
        float mn = fminf(fminf(ax - x1, ay - y1), fminf(x2 - ax, y2 - ay));
        if (mn > EPS_A)
          v = fmaxf(ciou_f(x1, y1, x2, y2, px1, py1, px2, py2), 0.f);
      }
      if (v > best){ best = v; bm = mm; }
    }
    mr = bm; ovl = fmaxf(best, 0.f);
  } else {
    mr = m;
    float x1 = gtbox[(b * MM + mr) * 4 + 0], y1 = gtbox[(b * MM + mr) * 4 + 1];
    float x2 = gtbox[(b * MM + mr) * 4 + 2], y2 = gtbox[(b * MM + mr) * 4 + 3];
    ovl = fmaxf(ciou_f(x1, y1, x2, y2, px1, py1, px2, py2), 0.f);
  }
  int lab = gtlab[b * MM + mr];
  float xv = L.f[(size_t)b * NOC * L.hw + (size_t)(4 * RM + lab) * L.hw + L.o];
  float sc = frcp(1.f + __expf(-xv));
  float o2 = ovl * ovl;
  float aln = sqrtf(sc) * (o2 * o2 * o2);
  size_t gi = (size_t)b * AT + a;
  resm[gi] = (unsigned char)mr;
  resaln[gi] = aln;
  atomicMax(&pa_i[b * MM + mr], __float_as_int(aln));
  atomicMax(&po_i[b * MM + mr], __float_as_int(ovl));
}

// ---------------- kernel 5: per-positive losses ----------------
__global__ __launch_bounds__(256) void k_final(
    const float* __restrict__ f0, const float* __restrict__ f1,
    const float* __restrict__ f2,
    const float4* __restrict__ pbox, const float4* __restrict__ lse,
    const float* __restrict__ gtbox, const int* __restrict__ gtlab,
    const int* __restrict__ pa_i, const int* __restrict__ po_i,
    const unsigned* __restrict__ mpos, const int* __restrict__ topk_arr,
    const unsigned char* __restrict__ resm, const float* __restrict__ resaln,
    double* __restrict__ acc){
  int i = blockIdx.x * 256 + threadIdx.x;
  float w_ = 0.f, clsp = 0.f, boxp = 0.f, dflp = 0.f;
  int a = topk_arr[i];
  if (a >= 0){
    int pair = i / TK;
    int b = pair / MM, m = pair % MM;
    unsigned bits = mpos[(size_t)b * AT + a];
    if (m == __ffs(bits) - 1){
      size_t gi = (size_t)b * AT + a;
      int mr = (int)resm[gi];
      float aln = resaln[gi];
      float pa = __int_as_float(pa_i[b * MM + mr]);
      float po = __int_as_float(po_i[b * MM + mr]);
      w_ = aln * po * frcp(pa + EPS_A);
      Lvl L = level_of(a, f0, f1, f2);
      const float* base = L.f + (size_t)b * NOC * L.hw + L.o;
      float ax = (float)(L.o % L.w) + 0.5f;
      float ay = (float)(L.o / L.w) + 0.5f;
      float inv_s = frcp(L.s);
      float tx1 = gtbox[(b * MM + mr) * 4 + 0] * inv_s, ty1 = gtbox[(b * MM + mr) * 4 + 1] * inv_s;
      float tx2 = gtbox[(b * MM + mr) * 4 + 2] * inv_s, ty2 = gtbox[(b * MM + mr) * 4 + 3] * inv_s;
      float4 pb = pbox[b * AT + a];
      float iou = ciou_f(pb.x, pb.y, pb.z, pb.w, tx1, ty1, tx2, ty2);
      boxp = (1.f - iou) * w_;
      float4 L4 = lse[b * AT + a];
      float lsv[4] = { L4.x, L4.y, L4.z, L4.w };
      float tv[4] = { ax - tx1, ay - ty1, tx2 - ax, ty2 - ay };
      float dfl = 0.f;
#pragma unroll
      for (int s4 = 0; s4 < 4; s4++){
        float t = fminf(fmaxf(tv[s4], 0.f), (float)(RM - 1) - 0.01f);
        int tl = (int)t;
        float wl = (float)(tl + 1) - t;
        float xl = base[(size_t)(s4 * RM + tl) * L.hw];
        float xr = base[(size_t)(s4 * RM + tl + 1) * L.hw];
        dfl += (lsv[s4] - xl) * wl + (lsv[s4] - xr) * (1.f - wl);
      }
      dflp = dfl * 0.25f * w_;
      int lab = gtlab[b * MM + mr];
      clsp = base[(size_t)(4 * RM + lab) * L.hw] * w_;
    }
  }
  __shared__ float red[4][4];
  float vals[4] = { w_, clsp, boxp, dflp };
  int wid = threadIdx.x >> 6, lid = threadIdx.x & 63;
#pragma unroll
  for (int j = 0; j < 4; j++){
    float v = vals[j];
    for (int off = 32; off; off >>= 1) v += __shfl_down(v, off);
    if (lid == 0) red[wid][j] = v;
  }
  __syncthreads();
  if (threadIdx.x == 0){
    float t0 = 0.f, t1 = 0.f, t2 = 0.f, t3 = 0.f;
    for (int w2 = 0; w2 < 4; w2++){
      t0 += red[w2][0]; t1 += red[w2][1]; t2 += red[w2][2]; t3 += red[w2][3];
    }
    atomicAdd(&acc[0], (double)t0);
    atomicAdd(&acc[1], (double)t1);
    atomicAdd(&acc[2], (double)t2);
    atomicAdd(&acc[3], (double)t3);
  }
}

// ---------------- kernel 6: finalize ----------------
__global__ void k_out(const double* __restrict__ acc, float* __restrict__ out){
  if (threadIdx.x == 0 && blockIdx.x == 0){
    double tss = acc[0] > 1.0 ? acc[0] : 1.0;
    double loss_box = acc[2] / tss;
    double loss_cls = (acc[4] - acc[1]) / tss;
    double loss_dfl = acc[3] / tss;
    float l0 = (float)(loss_box * 7.5);
    float l1 = (float)(loss_cls * 0.5);
    float l2 = (float)(loss_dfl * 1.5);
    out[0] = (l0 + l1 + l2) * 32.f;
    out[1] = l0;
    out[2] = l1;
    out[3] = l2;
  }
}

extern "C" void kernel_launch(void* const* d_in, const int* in_sizes, int n_in,
                              void* d_out, int out_size, void* d_ws, size_t ws_size,
                              hipStream_t stream) {
  const float* f0 = (const float*)d_in[0];
  const float* f1 = (const float*)d_in[1];
  const float* f2 = (const float*)d_in[2];
  const float* tg = (const float*)d_in[3];
  float* out = (float*)d_out;

  char* w = (char*)d_ws;
  size_t off = 0;
  auto alloc = [&](size_t bytes) -> void* {
    void* p = w + off;
    off += (bytes + 255) & ~(size_t)255;
    return p;
  };
  float4*        pbox    = (float4*)       alloc((size_t)BA * 16);
  float4*        lse     = (float4*)       alloc((size_t)BA * 16);
  float*         gtbox   = (float*)        alloc((size_t)BM * 16);
  int*           gtlab   = (int*)          alloc((size_t)BM * 4);
  float*         gtmask  = (float*)        alloc((size_t)BM * 4);
  float*         out5    = (float*)        alloc((size_t)BM * 20);
  unsigned*      mpos    = (unsigned*)     alloc((size_t)BA * 4);  // zeroed by k_feat
  int*           topk_arr= (int*)          alloc((size_t)MAXPOS * 4); // -1 by k_prep
  unsigned char* resm    = (unsigned char*)alloc((size_t)BA);      // write-before-read
  float*         resaln  = (float*)        alloc((size_t)BA * 4);  // write-before-read
  int*           pa      = (int*)          alloc((size_t)BM * 4);
  int*           po      = (int*)          alloc((size_t)BM * 4);
  double*        acc     = (double*)       alloc(8 * 8);

  k_prep<<<1, 640, 0, stream>>>(tg, out5, gtbox, gtlab, gtmask, pa, po, topk_arr, acc);
  k_feat<<<BB * NTILE, 256, 0, stream>>>(f0, f1, f2, pbox, lse, mpos, acc);
  k_align<<<BM, 256, 0, stream>>>(f0, f1, f2, pbox, gtbox, gtlab, gtmask, mpos, topk_arr);
  k_resolve<<<MAXPOS / 256, 256, 0, stream>>>(f0, f1, f2, pbox, gtbox, gtlab, gtmask,
                                              mpos, topk_arr, resm, resaln, pa, po);
  k_final<<<MAXPOS / 256, 256, 0, stream>>>(f0, f1, f2, pbox, lse, gtbox, gtlab,
                                            pa, po, mpos, topk_arr, resm, resaln, acc);
  k_out<<<1, 64, 0, stream>>>(acc, out);
}